// Round 1
// baseline (339.818 us; speedup 1.0000x reference)
//
#include <hip/hip_runtime.h>
#include <stdint.h>

// Problem constants
#define Bv  2
#define Tv  2048
#define Cv  1024
#define Hv  16
#define HDv 64
// M = Bv*Tv = 4096 rows for all projection GEMMs

typedef __bf16 bf16x8 __attribute__((ext_vector_type(8)));
typedef float f32x4 __attribute__((ext_vector_type(4)));
typedef unsigned short us4v __attribute__((ext_vector_type(4)));
typedef unsigned short us8v __attribute__((ext_vector_type(8)));

static __device__ __forceinline__ unsigned short f2bf(float f) {
    unsigned int u = __builtin_bit_cast(unsigned int, f);
    u += 0x7FFFu + ((u >> 16) & 1u);   // round-to-nearest-even
    return (unsigned short)(u >> 16);
}

static __device__ __forceinline__ void gld_lds16(const void* g, void* l) {
    __builtin_amdgcn_global_load_lds(
        (const __attribute__((address_space(1))) void*)g,
        (__attribute__((address_space(3))) void*)l, 16, 0, 0);
}

static __device__ __forceinline__ f32x4 mfma_bf16(bf16x8 a, bf16x8 b, f32x4 c) {
    return __builtin_amdgcn_mfma_f32_16x16x32_bf16(a, b, c, 0, 0, 0);
}

// ---------------- fp32 -> bf16 conversion ----------------
__global__ __launch_bounds__(256) void cvt_kernel(const float* __restrict__ in,
                                                  unsigned short* __restrict__ out,
                                                  int n) {
    int i = (blockIdx.x * 256 + threadIdx.x) * 4;
    if (i >= n) return;
    float4 v = *(const float4*)(in + i);
    us4v o;
    o[0] = f2bf(v.x); o[1] = f2bf(v.y); o[2] = f2bf(v.z); o[3] = f2bf(v.w);
    *(us4v*)(out + i) = o;
}

// ---------------- GEMM: C[m][n] = sum_k A[m][k]*B[n][k] + bias[n] ----------------
// A: [M][K] bf16 row-major, B: [N][K] bf16 row-major (i.e. x @ W^T with W[n][k]).
// mode 0: write bf16 head-split layout out[((b*H+h)*T+t)*HD+d]
// mode 1: write fp32 out[m*N+n]
__global__ __launch_bounds__(256) void gemm_bt(const unsigned short* __restrict__ A,
                                               const unsigned short* __restrict__ Bm,
                                               const float* __restrict__ bias,
                                               void* __restrict__ out,
                                               int M, int N, int K, int mode) {
    __shared__ unsigned short As[128 * 32];
    __shared__ unsigned short Bs[128 * 32];

    const int tid  = threadIdx.x;
    const int lane = tid & 63;
    const int w    = tid >> 6;
    const int wr   = w >> 1, wc = w & 1;
    const int m0   = blockIdx.y * 128;
    const int n0   = blockIdx.x * 128;
    const int l16  = lane & 15;
    const int lk8  = (lane >> 4) * 8;   // k-offset of this lane's 8 elements

    f32x4 acc[4][4] = {};

    // staging geometry: chunk c in {tid, tid+256}; row=c>>2, kc=(c&3)*8
    const int srow = tid >> 2;
    const int skc  = (tid & 3) * 8;

    for (int k0 = 0; k0 < K; k0 += 32) {
        const unsigned short* gA0 = A  + (size_t)(m0 + srow)      * K + k0 + skc;
        const unsigned short* gA1 = A  + (size_t)(m0 + srow + 64) * K + k0 + skc;
        const unsigned short* gB0 = Bm + (size_t)(n0 + srow)      * K + k0 + skc;
        const unsigned short* gB1 = Bm + (size_t)(n0 + srow + 64) * K + k0 + skc;
        gld_lds16(gA0, &As[(size_t)tid * 8]);
        gld_lds16(gA1, &As[(size_t)(tid + 256) * 8]);
        gld_lds16(gB0, &Bs[(size_t)tid * 8]);
        gld_lds16(gB1, &Bs[(size_t)(tid + 256) * 8]);
        __syncthreads();

        bf16x8 af[4], bf[4];
#pragma unroll
        for (int mf = 0; mf < 4; ++mf)
            af[mf] = *(const bf16x8*)&As[(wr * 64 + mf * 16 + l16) * 32 + lk8];
#pragma unroll
        for (int nf = 0; nf < 4; ++nf)
            bf[nf] = *(const bf16x8*)&Bs[(wc * 64 + nf * 16 + l16) * 32 + lk8];
#pragma unroll
        for (int mf = 0; mf < 4; ++mf)
#pragma unroll
            for (int nf = 0; nf < 4; ++nf)
                acc[mf][nf] = mfma_bf16(af[mf], bf[nf], acc[mf][nf]);
        __syncthreads();
    }

    // epilogue: C/D layout row=(lane>>4)*4+r, col=lane&15
#pragma unroll
    for (int mf = 0; mf < 4; ++mf) {
#pragma unroll
        for (int nf = 0; nf < 4; ++nf) {
#pragma unroll
            for (int r = 0; r < 4; ++r) {
                int m = m0 + wr * 64 + mf * 16 + (lane >> 4) * 4 + r;
                int n = n0 + wc * 64 + nf * 16 + l16;
                float v = acc[mf][nf][r] + bias[n];
                if (mode == 0) {
                    int b = m >> 11, t = m & (Tv - 1);
                    int h = n >> 6, d = n & (HDv - 1);
                    ((unsigned short*)out)[(((size_t)(b * Hv + h)) * Tv + t) * HDv + d] = f2bf(v);
                } else {
                    ((float*)out)[(size_t)m * N + n] = v;
                }
            }
        }
    }
}

// ---------------- causal flash attention ----------------
// q,k,v: [B*H][T][HD] bf16. y: [B][T][C] bf16 (head-merged).
__global__ __launch_bounds__(256) void attn_kernel(const unsigned short* __restrict__ q,
                                                   const unsigned short* __restrict__ k,
                                                   const unsigned short* __restrict__ v,
                                                   unsigned short* __restrict__ y) {
    __shared__ unsigned short P[4][16 * 32];

    const int lane = threadIdx.x & 63;
    const int w    = threadIdx.x >> 6;
    const int qt   = blockIdx.x;          // 0..T/64-1
    const int bh   = blockIdx.y;          // 0..B*H-1
    const int b    = bh >> 4, h = bh & (Hv - 1);
    const int qr0  = qt * 64 + w * 16;    // this wave's first q row
    const int l16  = lane & 15;
    const int lk   = lane >> 4;           // 0..3
    const size_t head_off = (size_t)bh * Tv * HDv;

    // Q fragments (held whole kernel): rows qr0+l16, d-chunks 0-31 / 32-63
    bf16x8 qf[2];
    {
        const unsigned short* qp = q + head_off + (size_t)(qr0 + l16) * HDv + lk * 8;
        qf[0] = *(const bf16x8*)qp;
        qf[1] = *(const bf16x8*)(qp + 32);
    }

    f32x4 acc[4] = {};
    float mrow[4] = {-1e30f, -1e30f, -1e30f, -1e30f};
    float lrow[4] = {};

    const int nkt = (qr0 + 15) / 32 + 1;  // 32-wide K tiles (causal bound)
    for (int kt = 0; kt < nkt; ++kt) {
        const int kk0 = kt * 32;

        // S = Q K^T over 32 k-rows (two 16-col tiles), d=64 split in two K=32 MFMAs
        f32x4 s[2];
#pragma unroll
        for (int ct = 0; ct < 2; ++ct) {
            const unsigned short* kp = k + head_off + (size_t)(kk0 + ct * 16 + l16) * HDv + lk * 8;
            bf16x8 k0f = *(const bf16x8*)kp;
            bf16x8 k1f = *(const bf16x8*)(kp + 32);
            f32x4 z = {};
            z = mfma_bf16(qf[0], k0f, z);
            z = mfma_bf16(qf[1], k1f, z);
            s[ct] = z;
        }

        // scale + causal mask
#pragma unroll
        for (int ct = 0; ct < 2; ++ct)
#pragma unroll
            for (int r = 0; r < 4; ++r) {
                int ig = qr0 + lk * 4 + r;
                int jg = kk0 + ct * 16 + l16;
                float val = s[ct][r] * 0.125f;   // 1/sqrt(64)
                s[ct][r] = (jg <= ig) ? val : -1e30f;
            }

        // online softmax per row r (row's 16 cols live in the 16-lane group)
        float pl[2][4];
#pragma unroll
        for (int r = 0; r < 4; ++r) {
            float mx = fmaxf(s[0][r], s[1][r]);
#pragma unroll
            for (int off = 8; off >= 1; off >>= 1)
                mx = fmaxf(mx, __shfl_xor(mx, off));
            float mnew  = fmaxf(mrow[r], mx);
            float alpha = __expf(mrow[r] - mnew);
            float p0 = __expf(s[0][r] - mnew);
            float p1 = __expf(s[1][r] - mnew);
            float ps = p0 + p1;
#pragma unroll
            for (int off = 8; off >= 1; off >>= 1)
                ps += __shfl_xor(ps, off);
            lrow[r] = lrow[r] * alpha + ps;
            mrow[r] = mnew;
            acc[0][r] *= alpha; acc[1][r] *= alpha;
            acc[2][r] *= alpha; acc[3][r] *= alpha;
            pl[0][r] = p0; pl[1][r] = p1;
        }

        // P -> LDS (C/D layout) then read back as A fragment
        unsigned short* pb = &P[w][0];
#pragma unroll
        for (int ct = 0; ct < 2; ++ct)
#pragma unroll
            for (int r = 0; r < 4; ++r)
                pb[(lk * 4 + r) * 32 + ct * 16 + l16] = f2bf(pl[ct][r]);
        bf16x8 pf = *(const bf16x8*)&pb[l16 * 32 + lk * 8];

        // PV: acc[nt] += P(16x32) * V(32x16)
#pragma unroll
        for (int nt = 0; nt < 4; ++nt) {
            us8v vv;
#pragma unroll
            for (int i = 0; i < 8; ++i)
                vv[i] = v[head_off + (size_t)(kk0 + lk * 8 + i) * HDv + nt * 16 + l16];
            acc[nt] = mfma_bf16(pf, __builtin_bit_cast(bf16x8, vv), acc[nt]);
        }
    }

    // normalize + write y (head-merged [B][T][C])
#pragma unroll
    for (int nt = 0; nt < 4; ++nt)
#pragma unroll
        for (int r = 0; r < 4; ++r) {
            int t = qr0 + lk * 4 + r;
            float val = acc[nt][r] / lrow[r];
            y[((size_t)(b * Tv + t)) * Cv + h * HDv + nt * 16 + l16] = f2bf(val);
        }
}

extern "C" void kernel_launch(void* const* d_in, const int* in_sizes, int n_in,
                              void* d_out, int out_size, void* d_ws, size_t ws_size,
                              hipStream_t stream) {
    const float* x  = (const float*)d_in[0];
    const float* Wk = (const float*)d_in[1];
    const float* bk = (const float*)d_in[2];
    const float* Wq = (const float*)d_in[3];
    const float* bq = (const float*)d_in[4];
    const float* Wv = (const float*)d_in[5];
    const float* bv = (const float*)d_in[6];
    const float* Wp = (const float*)d_in[7];
    const float* bp = (const float*)d_in[8];

    // workspace layout (ushorts); total 40 MB
    unsigned short* ws  = (unsigned short*)d_ws;
    unsigned short* xb  = ws;                  // 4194304 (also reused as yb)
    unsigned short* wkb = xb  + 4194304;       // 1048576
    unsigned short* wqb = wkb + 1048576;
    unsigned short* wvb = wqb + 1048576;
    unsigned short* wpb = wvb + 1048576;
    unsigned short* qb  = wpb + 1048576;       // 4194304 each, head-split
    unsigned short* kb  = qb  + 4194304;
    unsigned short* vb  = kb  + 4194304;
    unsigned short* yb  = xb;                  // reuse: x dead after QKV GEMMs

    cvt_kernel<<<4096, 256, 0, stream>>>(x,  xb,  4194304);
    cvt_kernel<<<1024, 256, 0, stream>>>(Wk, wkb, 1048576);
    cvt_kernel<<<1024, 256, 0, stream>>>(Wq, wqb, 1048576);
    cvt_kernel<<<1024, 256, 0, stream>>>(Wv, wvb, 1048576);
    cvt_kernel<<<1024, 256, 0, stream>>>(Wp, wpb, 1048576);

    dim3 gg(Cv / 128, (Bv * Tv) / 128);   // (8, 32)
    gemm_bt<<<gg, 256, 0, stream>>>(xb, wqb, bq, qb, Bv * Tv, Cv, Cv, 0);
    gemm_bt<<<gg, 256, 0, stream>>>(xb, wkb, bk, kb, Bv * Tv, Cv, Cv, 0);
    gemm_bt<<<gg, 256, 0, stream>>>(xb, wvb, bv, vb, Bv * Tv, Cv, Cv, 0);

    attn_kernel<<<dim3(Tv / 64, Bv * Hv), 256, 0, stream>>>(qb, kb, vb, yb);

    gemm_bt<<<gg, 256, 0, stream>>>(yb, wpb, bp, d_out, Bv * Tv, Cv, Cv, 1);
}

// Round 2
// 332.904 us; speedup vs baseline: 1.0208x; 1.0208x over previous
//
#include <hip/hip_runtime.h>
#include <stdint.h>

// Problem constants
#define Bv  2
#define Tv  2048
#define Cv  1024
#define Hv  16
#define HDv 64
// M = Bv*Tv = 4096 rows for all projection GEMMs

typedef __bf16 bf16x8 __attribute__((ext_vector_type(8)));
typedef float f32x4 __attribute__((ext_vector_type(4)));
typedef unsigned short us4v __attribute__((ext_vector_type(4)));

static __device__ __forceinline__ unsigned short f2bf(float f) {
    unsigned int u = __builtin_bit_cast(unsigned int, f);
    u += 0x7FFFu + ((u >> 16) & 1u);   // round-to-nearest-even
    return (unsigned short)(u >> 16);
}

static __device__ __forceinline__ void gld_lds16(const void* g, void* l) {
    __builtin_amdgcn_global_load_lds(
        (const __attribute__((address_space(1))) void*)g,
        (__attribute__((address_space(3))) void*)l, 16, 0, 0);
}

static __device__ __forceinline__ f32x4 mfma_bf16(bf16x8 a, bf16x8 b, f32x4 c) {
    return __builtin_amdgcn_mfma_f32_16x16x32_bf16(a, b, c, 0, 0, 0);
}

// ---------------- fp32 -> bf16 conversion ----------------
__global__ __launch_bounds__(256) void cvt_kernel(const float* __restrict__ in,
                                                  unsigned short* __restrict__ out,
                                                  int n) {
    int i = (blockIdx.x * 256 + threadIdx.x) * 4;
    if (i >= n) return;
    float4 v = *(const float4*)(in + i);
    us4v o;
    o[0] = f2bf(v.x); o[1] = f2bf(v.y); o[2] = f2bf(v.z); o[3] = f2bf(v.w);
    *(us4v*)(out + i) = o;
}

// ---------------- GEMM: C[m][n] = sum_k A[m][k]*B[n][k] (+bias, scaled) ----------------
// mode 0: out bf16 head-split [((b*H+h)*T+t)*HD+d], bias[n], *scale
// mode 1: out fp32 [m*N+n], bias[n]
// mode 2: out bf16 V-transposed: out[(b*1024 + m)*T + t] with n=(b,t), bias[m]
__global__ __launch_bounds__(256) void gemm_bt(const unsigned short* __restrict__ A,
                                               const unsigned short* __restrict__ Bm,
                                               const float* __restrict__ bias,
                                               void* __restrict__ out,
                                               int M, int N, int K, int mode, float scale) {
    __shared__ unsigned short As[128 * 32];
    __shared__ unsigned short Bs[128 * 32];

    const int tid  = threadIdx.x;
    const int lane = tid & 63;
    const int w    = tid >> 6;
    const int wr   = w >> 1, wc = w & 1;
    const int m0   = blockIdx.y * 128;
    const int n0   = blockIdx.x * 128;
    const int l16  = lane & 15;
    const int lk8  = (lane >> 4) * 8;

    f32x4 acc[4][4] = {};

    const int srow = tid >> 2;
    const int skc  = (tid & 3) * 8;

    for (int k0 = 0; k0 < K; k0 += 32) {
        const unsigned short* gA0 = A  + (size_t)(m0 + srow)      * K + k0 + skc;
        const unsigned short* gA1 = A  + (size_t)(m0 + srow + 64) * K + k0 + skc;
        const unsigned short* gB0 = Bm + (size_t)(n0 + srow)      * K + k0 + skc;
        const unsigned short* gB1 = Bm + (size_t)(n0 + srow + 64) * K + k0 + skc;
        gld_lds16(gA0, &As[(size_t)tid * 8]);
        gld_lds16(gA1, &As[(size_t)(tid + 256) * 8]);
        gld_lds16(gB0, &Bs[(size_t)tid * 8]);
        gld_lds16(gB1, &Bs[(size_t)(tid + 256) * 8]);
        __syncthreads();

        bf16x8 af[4], bf[4];
#pragma unroll
        for (int mf = 0; mf < 4; ++mf)
            af[mf] = *(const bf16x8*)&As[(wr * 64 + mf * 16 + l16) * 32 + lk8];
#pragma unroll
        for (int nf = 0; nf < 4; ++nf)
            bf[nf] = *(const bf16x8*)&Bs[(wc * 64 + nf * 16 + l16) * 32 + lk8];
#pragma unroll
        for (int mf = 0; mf < 4; ++mf)
#pragma unroll
            for (int nf = 0; nf < 4; ++nf)
                acc[mf][nf] = mfma_bf16(af[mf], bf[nf], acc[mf][nf]);
        __syncthreads();
    }

    // epilogue: C/D layout row=(lane>>4)*4+r, col=lane&15
#pragma unroll
    for (int mf = 0; mf < 4; ++mf) {
#pragma unroll
        for (int nf = 0; nf < 4; ++nf) {
#pragma unroll
            for (int r = 0; r < 4; ++r) {
                int m = m0 + wr * 64 + mf * 16 + (lane >> 4) * 4 + r;
                int n = n0 + wc * 64 + nf * 16 + l16;
                if (mode == 0) {
                    float v = (acc[mf][nf][r] + bias[n]) * scale;
                    int b = m >> 11, t = m & (Tv - 1);
                    int h = n >> 6, d = n & (HDv - 1);
                    ((unsigned short*)out)[(((size_t)(b * Hv + h)) * Tv + t) * HDv + d] = f2bf(v);
                } else if (mode == 2) {
                    // m = channel (h*64+d), n = token (b*2048+t)
                    float v = (acc[mf][nf][r] + bias[m]) * scale;
                    ((unsigned short*)out)[((size_t)(n >> 11) * 1024 + m) * Tv + (n & (Tv - 1))] = f2bf(v);
                } else {
                    ((float*)out)[(size_t)m * N + n] = acc[mf][nf][r] + bias[n];
                }
            }
        }
    }
}

// ---------------- causal flash attention ----------------
// q,k: [B*H][T][HD] bf16 (q pre-scaled by 1/8). vt: [B*H][HD][T] bf16.
// y: [B][T][C] bf16 (head-merged).
__global__ __launch_bounds__(256) void attn_kernel(const unsigned short* __restrict__ q,
                                                   const unsigned short* __restrict__ k,
                                                   const unsigned short* __restrict__ vt,
                                                   unsigned short* __restrict__ y) {
    __shared__ __align__(16) unsigned short P[4][16 * 64];

    const int lane = threadIdx.x & 63;
    const int w    = threadIdx.x >> 6;

    // XCD-aware mapping: 8 XCDs x 4 heads x 32 q-tiles (bijective over 1024)
    const int lb  = blockIdx.x;
    const int xcd = lb & 7;
    const int idx = lb >> 3;            // 0..127
    const int bh  = xcd * 4 + (idx >> 5);
    const int qt  = idx & 31;

    const int b   = bh >> 4, h = bh & (Hv - 1);
    const int qr0 = qt * 64 + w * 16;
    const int l16 = lane & 15;
    const int lk  = lane >> 4;
    const size_t head_off = (size_t)bh * Tv * HDv;
    const unsigned short* vth = vt + head_off;   // rows: d (64), cols: t (2048)

    // Q fragments (rows qr0+l16, d-chunks 0-31 / 32-63), held in regs
    bf16x8 qf0, qf1;
    {
        const unsigned short* qp = q + head_off + (size_t)(qr0 + l16) * HDv + lk * 8;
        qf0 = *(const bf16x8*)qp;
        qf1 = *(const bf16x8*)(qp + 32);
    }

    f32x4 acc[4] = {};
    float mrow[4] = {-1e30f, -1e30f, -1e30f, -1e30f};
    float lrow[4] = {};
    unsigned short* pb = &P[w][0];
    const int swr = l16 & 7;            // read-side swizzle key

    const int nkt = qt + 1;             // 64-wide K tiles (causal bound)
    for (int kt = 0; kt < nkt; ++kt) {
        const int kk0 = kt * 64;

        // S = Q K^T over 64 k-rows (four 16-col tiles), d=64 in two K=32 MFMAs
        f32x4 s[4];
#pragma unroll
        for (int ct = 0; ct < 4; ++ct) {
            const unsigned short* kp = k + head_off + (size_t)(kk0 + ct * 16 + l16) * HDv + lk * 8;
            bf16x8 k0f = *(const bf16x8*)kp;
            bf16x8 k1f = *(const bf16x8*)(kp + 32);
            f32x4 z = {};
            z = mfma_bf16(qf0, k0f, z);
            z = mfma_bf16(qf1, k1f, z);
            s[ct] = z;
        }

        // causal mask (only the last/diagonal tile needs it; q pre-scaled)
        if (kt == nkt - 1) {
#pragma unroll
            for (int ct = 0; ct < 4; ++ct)
#pragma unroll
                for (int r = 0; r < 4; ++r) {
                    int ig = qr0 + lk * 4 + r;
                    int jg = kk0 + ct * 16 + l16;
                    if (jg > ig) s[ct][r] = -1e30f;
                }
        }

        // online softmax per row r (row's 16 cols live in the 16-lane group)
        float pl[4][4];
#pragma unroll
        for (int r = 0; r < 4; ++r) {
            float mx = fmaxf(fmaxf(s[0][r], s[1][r]), fmaxf(s[2][r], s[3][r]));
#pragma unroll
            for (int off = 8; off >= 1; off >>= 1)
                mx = fmaxf(mx, __shfl_xor(mx, off));
            float mnew  = fmaxf(mrow[r], mx);
            float alpha = __expf(mrow[r] - mnew);
            float ps = 0.f;
#pragma unroll
            for (int ct = 0; ct < 4; ++ct) {
                pl[ct][r] = __expf(s[ct][r] - mnew);
                ps += pl[ct][r];
            }
#pragma unroll
            for (int off = 8; off >= 1; off >>= 1)
                ps += __shfl_xor(ps, off);
            lrow[r] = lrow[r] * alpha + ps;
            mrow[r] = mnew;
            acc[0][r] *= alpha; acc[1][r] *= alpha;
            acc[2][r] *= alpha; acc[3][r] *= alpha;
        }

        // P -> LDS (XOR-swizzled granules: col granule ^= row&7) then read as A frag
#pragma unroll
        for (int ct = 0; ct < 4; ++ct) {
            int g = ct * 2 + (l16 >> 3);
#pragma unroll
            for (int r = 0; r < 4; ++r) {
                int row = lk * 4 + r;
                pb[row * 64 + (((g ^ (row & 7)) << 3) | (l16 & 7))] = f2bf(pl[ct][r]);
            }
        }
        bf16x8 pf0 = *(const bf16x8*)&pb[l16 * 64 + ((lk       ^ swr) << 3)];
        bf16x8 pf1 = *(const bf16x8*)&pb[l16 * 64 + (((4 + lk) ^ swr) << 3)];

        // PV: acc[nt] += P(16x64) * V(64x16); V^T rows are contiguous in k
#pragma unroll
        for (int nt = 0; nt < 4; ++nt) {
            const unsigned short* vp = vth + (size_t)(nt * 16 + l16) * Tv + kk0 + lk * 8;
            bf16x8 v0 = *(const bf16x8*)vp;
            bf16x8 v1 = *(const bf16x8*)(vp + 32);
            acc[nt] = mfma_bf16(pf0, v0, acc[nt]);
            acc[nt] = mfma_bf16(pf1, v1, acc[nt]);
        }
    }

    // normalize + write y (head-merged [B][T][C])
#pragma unroll
    for (int nt = 0; nt < 4; ++nt)
#pragma unroll
        for (int r = 0; r < 4; ++r) {
            int t = qr0 + lk * 4 + r;
            float val = acc[nt][r] / lrow[r];
            y[((size_t)(b * Tv + t)) * Cv + h * HDv + nt * 16 + l16] = f2bf(val);
        }
}

extern "C" void kernel_launch(void* const* d_in, const int* in_sizes, int n_in,
                              void* d_out, int out_size, void* d_ws, size_t ws_size,
                              hipStream_t stream) {
    const float* x  = (const float*)d_in[0];
    const float* Wk = (const float*)d_in[1];
    const float* bk = (const float*)d_in[2];
    const float* Wq = (const float*)d_in[3];
    const float* bq = (const float*)d_in[4];
    const float* Wv = (const float*)d_in[5];
    const float* bv = (const float*)d_in[6];
    const float* Wp = (const float*)d_in[7];
    const float* bp = (const float*)d_in[8];

    // workspace layout (ushorts); total 40 MB
    unsigned short* ws  = (unsigned short*)d_ws;
    unsigned short* xb  = ws;                  // 4194304 (reused as yb)
    unsigned short* wkb = xb  + 4194304;       // 1048576
    unsigned short* wqb = wkb + 1048576;
    unsigned short* wvb = wqb + 1048576;
    unsigned short* wpb = wvb + 1048576;
    unsigned short* qb  = wpb + 1048576;       // head-split, q pre-scaled
    unsigned short* kb  = qb  + 4194304;       // head-split
    unsigned short* vtb = kb  + 4194304;       // V transposed [B*H][HD][T]
    unsigned short* yb  = xb;                  // reuse: x dead after QKV GEMMs

    cvt_kernel<<<4096, 256, 0, stream>>>(x,  xb,  4194304);
    cvt_kernel<<<1024, 256, 0, stream>>>(Wk, wkb, 1048576);
    cvt_kernel<<<1024, 256, 0, stream>>>(Wq, wqb, 1048576);
    cvt_kernel<<<1024, 256, 0, stream>>>(Wv, wvb, 1048576);
    cvt_kernel<<<1024, 256, 0, stream>>>(Wp, wpb, 1048576);

    dim3 gg(Cv / 128, (Bv * Tv) / 128);   // (8, 32)
    gemm_bt<<<gg, 256, 0, stream>>>(xb, wqb, bq, qb, Bv * Tv, Cv, Cv, 0, 0.125f);
    gemm_bt<<<gg, 256, 0, stream>>>(xb, wkb, bk, kb, Bv * Tv, Cv, Cv, 0, 1.0f);
    // V computed transposed: C[c][tok] = sum_k Wv[c][k] * x[tok][k]  (bias by row)
    dim3 gv((Bv * Tv) / 128, Cv / 128);   // (32, 8)
    gemm_bt<<<gv, 256, 0, stream>>>(wvb, xb, bv, vtb, Cv, Bv * Tv, Cv, 2, 1.0f);

    attn_kernel<<<1024, 256, 0, stream>>>(qb, kb, vtb, yb);

    gemm_bt<<<gg, 256, 0, stream>>>(yb, wpb, bp, d_out, Bv * Tv, Cv, Cv, 1, 1.0f);
}

// Round 3
// 285.223 us; speedup vs baseline: 1.1914x; 1.1672x over previous
//
#include <hip/hip_runtime.h>
#include <stdint.h>

// Problem constants
#define Bv  2
#define Tv  2048
#define Cv  1024
#define Hv  16
#define HDv 64

typedef __bf16 bf16x8 __attribute__((ext_vector_type(8)));
typedef float f32x4 __attribute__((ext_vector_type(4)));
typedef unsigned short us4v __attribute__((ext_vector_type(4)));

static __device__ __forceinline__ unsigned short f2bf(float f) {
    unsigned int u = __builtin_bit_cast(unsigned int, f);
    u += 0x7FFFu + ((u >> 16) & 1u);   // round-to-nearest-even
    return (unsigned short)(u >> 16);
}

static __device__ __forceinline__ unsigned int cvt_pk_bf16(float lo, float hi) {
    unsigned int w;
    asm("v_cvt_pk_bf16_f32 %0, %1, %2" : "=v"(w) : "v"(lo), "v"(hi));
    return w;
}

static __device__ __forceinline__ void gld_lds16(const void* g, void* l) {
    __builtin_amdgcn_global_load_lds(
        (const __attribute__((address_space(1))) void*)g,
        (__attribute__((address_space(3))) void*)l, 16, 0, 0);
}

static __device__ __forceinline__ f32x4 mfma_bf16(bf16x8 a, bf16x8 b, f32x4 c) {
    return __builtin_amdgcn_mfma_f32_16x16x32_bf16(a, b, c, 0, 0, 0);
}

static __device__ __forceinline__ f32x4 fmax4(f32x4 a, f32x4 b) {
    f32x4 r;
    r[0] = fmaxf(a[0], b[0]); r[1] = fmaxf(a[1], b[1]);
    r[2] = fmaxf(a[2], b[2]); r[3] = fmaxf(a[3], b[3]);
    return r;
}

// ---------------- fp32 -> bf16 conversion ----------------
__global__ __launch_bounds__(256) void cvt_kernel(const float* __restrict__ in,
                                                  unsigned short* __restrict__ out,
                                                  int n) {
    int i = (blockIdx.x * 256 + threadIdx.x) * 4;
    if (i >= n) return;
    float4 v = *(const float4*)(in + i);
    us4v o;
    o[0] = f2bf(v.x); o[1] = f2bf(v.y); o[2] = f2bf(v.z); o[3] = f2bf(v.w);
    *(us4v*)(out + i) = o;
}

// ---------------- GEMM: C[m][n] = sum_k A[m][k]*B[n][k] (+bias, scaled) ----------------
// mode 0: out bf16 head-split [((b*H+h)*T+t)*HD+d], bias[n], *scale
// mode 1: out fp32 [m*N+n], bias[n]
// mode 2: out bf16 V-transposed: out[(b*1024 + m)*T + t] with n=(b,t), bias[m]
__global__ __launch_bounds__(256) void gemm_bt(const unsigned short* __restrict__ A,
                                               const unsigned short* __restrict__ Bm,
                                               const float* __restrict__ bias,
                                               void* __restrict__ out,
                                               int M, int N, int K, int mode, float scale) {
    __shared__ unsigned short As[128 * 32];
    __shared__ unsigned short Bs[128 * 32];

    const int tid  = threadIdx.x;
    const int lane = tid & 63;
    const int w    = tid >> 6;
    const int wr   = w >> 1, wc = w & 1;
    const int m0   = blockIdx.y * 128;
    const int n0   = blockIdx.x * 128;
    const int l16  = lane & 15;
    const int lk8  = (lane >> 4) * 8;

    f32x4 acc[4][4] = {};

    const int srow = tid >> 2;
    const int skc  = (tid & 3) * 8;

    for (int k0 = 0; k0 < K; k0 += 32) {
        const unsigned short* gA0 = A  + (size_t)(m0 + srow)      * K + k0 + skc;
        const unsigned short* gA1 = A  + (size_t)(m0 + srow + 64) * K + k0 + skc;
        const unsigned short* gB0 = Bm + (size_t)(n0 + srow)      * K + k0 + skc;
        const unsigned short* gB1 = Bm + (size_t)(n0 + srow + 64) * K + k0 + skc;
        gld_lds16(gA0, &As[(size_t)tid * 8]);
        gld_lds16(gA1, &As[(size_t)(tid + 256) * 8]);
        gld_lds16(gB0, &Bs[(size_t)tid * 8]);
        gld_lds16(gB1, &Bs[(size_t)(tid + 256) * 8]);
        __syncthreads();

        bf16x8 af[4], bf[4];
#pragma unroll
        for (int mf = 0; mf < 4; ++mf)
            af[mf] = *(const bf16x8*)&As[(wr * 64 + mf * 16 + l16) * 32 + lk8];
#pragma unroll
        for (int nf = 0; nf < 4; ++nf)
            bf[nf] = *(const bf16x8*)&Bs[(wc * 64 + nf * 16 + l16) * 32 + lk8];
#pragma unroll
        for (int mf = 0; mf < 4; ++mf)
#pragma unroll
            for (int nf = 0; nf < 4; ++nf)
                acc[mf][nf] = mfma_bf16(af[mf], bf[nf], acc[mf][nf]);
        __syncthreads();
    }

    // epilogue: C/D layout row=(lane>>4)*4+r, col=lane&15
#pragma unroll
    for (int mf = 0; mf < 4; ++mf) {
#pragma unroll
        for (int nf = 0; nf < 4; ++nf) {
#pragma unroll
            for (int r = 0; r < 4; ++r) {
                int m = m0 + wr * 64 + mf * 16 + (lane >> 4) * 4 + r;
                int n = n0 + wc * 64 + nf * 16 + l16;
                if (mode == 0) {
                    float v = (acc[mf][nf][r] + bias[n]) * scale;
                    int b = m >> 11, t = m & (Tv - 1);
                    int h = n >> 6, d = n & (HDv - 1);
                    ((unsigned short*)out)[(((size_t)(b * Hv + h)) * Tv + t) * HDv + d] = f2bf(v);
                } else if (mode == 2) {
                    // m = channel (h*64+d), n = token (b*2048+t)
                    float v = (acc[mf][nf][r] + bias[m]) * scale;
                    ((unsigned short*)out)[((size_t)(n >> 11) * 1024 + m) * Tv + (n & (Tv - 1))] = f2bf(v);
                } else {
                    ((float*)out)[(size_t)m * N + n] = acc[mf][nf][r] + bias[n];
                }
            }
        }
    }
}

// ---------------- causal flash attention (swapped-operand layout) ----------------
// q,k: [B*H][T][HD] bf16 (q pre-scaled by 1/8). vt: [B*H][HD][T] bf16.
// y: [B][T][C] bf16 (head-merged).
// Per wave: 16 q-rows, KVBLK=128. S^T = K*Q^T so q is lane-local (col=l16);
// PV computed transposed: O^T = V^T * P^T, so softmax stats/rescale/output all lane-local.
// Block = (head, tile-pair(t,31-t), row-half): every wave does exactly 17 K-tiles.
__global__ __launch_bounds__(128) void attn_kernel(const unsigned short* __restrict__ q,
                                                   const unsigned short* __restrict__ k,
                                                   const unsigned short* __restrict__ vt,
                                                   unsigned short* __restrict__ y) {
    __shared__ __align__(16) unsigned short Pb[2][16 * 132];   // +4 shorts row pad: conflict-free b64

    const int tid  = threadIdx.x;
    const int lane = tid & 63;
    const int w    = tid >> 6;
    const int l16  = lane & 15;
    const int lk   = lane >> 4;

    // XCD-pinned mapping: 8 XCDs x 4 heads x (16 pairs x 2 halves)
    const int lb   = blockIdx.x;
    const int xcd  = lb & 7;
    const int rest = lb >> 3;              // 0..127
    const int bh   = xcd * 4 + (rest >> 5);
    const int pr   = (rest & 31) >> 1;     // pair index 0..15
    const int half = rest & 1;

    const int b = bh >> 4, h = bh & (Hv - 1);
    const size_t head_off = (size_t)bh * (Tv * HDv);
    const unsigned short* kpb = k  + head_off;
    const unsigned short* vpb = vt + head_off;   // [HD][T]
    unsigned short* pb = &Pb[w][0];
    const int prow = l16 * 132;

    for (int phase = 0; phase < 2; ++phase) {
        const int tile = phase ? (31 - pr) : pr;
        const int qr0  = tile * 64 + half * 32 + w * 16;
        const int qg   = qr0 + l16;

        // Q as B-fragment: col=q (l16), k-dim = d
        bf16x8 qf0, qf1;
        {
            const unsigned short* qp = q + head_off + (size_t)qg * HDv + lk * 8;
            qf0 = *(const bf16x8*)qp;
            qf1 = *(const bf16x8*)(qp + 32);
        }

        f32x4 acc[4] = {};           // O^T: acc[nt], row d = nt*16+lk*4+r, col q = l16
        float m = -1e38f, l = 0.f;

        const int nkt = (tile + 2) >> 1;
        for (int j = 0; j < nkt; ++j) {
            const int kk0 = j * 128;

            // S^T = K Q^T : s[ct][r] = S[k = kk0+ct*16+lk*4+r][q = l16]
            f32x4 s[8];
#pragma unroll
            for (int ct = 0; ct < 8; ++ct) {
                const unsigned short* kp = kpb + (size_t)(kk0 + ct * 16 + l16) * HDv + lk * 8;
                bf16x8 k0 = *(const bf16x8*)kp;
                bf16x8 k1 = *(const bf16x8*)(kp + 32);
                f32x4 z = {};
                z = mfma_bf16(k0, qf0, z);
                z = mfma_bf16(k1, qf1, z);
                s[ct] = z;
            }

            // V^T fragments issued early (independent of softmax) to hide L2 latency
            bf16x8 vf[4][4];
#pragma unroll
            for (int nt = 0; nt < 4; ++nt)
#pragma unroll
                for (int kh = 0; kh < 4; ++kh)
                    vf[nt][kh] = *(const bf16x8*)(vpb + (size_t)(nt * 16 + l16) * Tv + kk0 + kh * 32 + lk * 8);

            // causal mask (only tiles overlapping the diagonal)
            if (kk0 + 127 > qr0) {
#pragma unroll
                for (int ct = 0; ct < 8; ++ct) {
                    const int kb2 = kk0 + ct * 16 + lk * 4;
#pragma unroll
                    for (int r = 0; r < 4; ++r)
                        if (kb2 + r > qg) s[ct][r] = -1e38f;
                }
            }

            // online softmax: 31 in-register fmax + 2 shuffles
            f32x4 t0 = fmax4(fmax4(s[0], s[1]), fmax4(s[2], s[3]));
            f32x4 t1 = fmax4(fmax4(s[4], s[5]), fmax4(s[6], s[7]));
            t0 = fmax4(t0, t1);
            float pm = fmaxf(fmaxf(t0[0], t0[1]), fmaxf(t0[2], t0[3]));
            pm = fmaxf(pm, __shfl_xor(pm, 16));
            pm = fmaxf(pm, __shfl_xor(pm, 32));

            const float mnew  = fmaxf(m, pm);
            const float alpha = __expf(m - mnew);

            f32x4 ps4 = {};
#pragma unroll
            for (int ct = 0; ct < 8; ++ct) {
#pragma unroll
                for (int r = 0; r < 4; ++r)
                    s[ct][r] = __expf(s[ct][r] - mnew);
                ps4 += s[ct];
            }
            float psum = (ps4[0] + ps4[1]) + (ps4[2] + ps4[3]);
            psum += __shfl_xor(psum, 16);
            psum += __shfl_xor(psum, 32);

            l = l * alpha + psum;
            m = mnew;
#pragma unroll
            for (int nt = 0; nt < 4; ++nt)
                acc[nt] *= alpha;

            // P^T -> LDS rows=q, cols=k (b64 writes, conflict-free via +4 pad)
#pragma unroll
            for (int ct = 0; ct < 8; ++ct) {
                uint2 wv;
                wv.x = cvt_pk_bf16(s[ct][0], s[ct][1]);
                wv.y = cvt_pk_bf16(s[ct][2], s[ct][3]);
                *(uint2*)&pb[prow + ct * 16 + lk * 4] = wv;
            }

            // O^T += V^T * P^T
#pragma unroll
            for (int kh = 0; kh < 4; ++kh) {
                union { us4v p[2]; bf16x8 f; } u;
                u.p[0] = *(const us4v*)&pb[prow + kh * 32 + lk * 8];
                u.p[1] = *(const us4v*)&pb[prow + kh * 32 + lk * 8 + 4];
#pragma unroll
                for (int nt = 0; nt < 4; ++nt)
                    acc[nt] = mfma_bf16(vf[nt][kh], u.f, acc[nt]);
            }
        }

        // epilogue: lane-local normalize, packed 8B stores
        const float rl = 1.0f / l;
        const size_t ybase = ((size_t)(b * Tv + qg)) * Cv + h * HDv + lk * 4;
#pragma unroll
        for (int nt = 0; nt < 4; ++nt) {
            uint2 wv;
            wv.x = cvt_pk_bf16(acc[nt][0] * rl, acc[nt][1] * rl);
            wv.y = cvt_pk_bf16(acc[nt][2] * rl, acc[nt][3] * rl);
            *(uint2*)&y[ybase + nt * 16] = wv;
        }
    }
}

extern "C" void kernel_launch(void* const* d_in, const int* in_sizes, int n_in,
                              void* d_out, int out_size, void* d_ws, size_t ws_size,
                              hipStream_t stream) {
    const float* x  = (const float*)d_in[0];
    const float* Wk = (const float*)d_in[1];
    const float* bk = (const float*)d_in[2];
    const float* Wq = (const float*)d_in[3];
    const float* bq = (const float*)d_in[4];
    const float* Wv = (const float*)d_in[5];
    const float* bv = (const float*)d_in[6];
    const float* Wp = (const float*)d_in[7];
    const float* bp = (const float*)d_in[8];

    // workspace layout (ushorts); total 40 MB
    unsigned short* ws  = (unsigned short*)d_ws;
    unsigned short* xb  = ws;                  // 4194304 (reused as yb)
    unsigned short* wkb = xb  + 4194304;       // 1048576
    unsigned short* wqb = wkb + 1048576;
    unsigned short* wvb = wqb + 1048576;
    unsigned short* wpb = wvb + 1048576;
    unsigned short* qb  = wpb + 1048576;       // head-split, q pre-scaled by 1/8
    unsigned short* kb  = qb  + 4194304;       // head-split
    unsigned short* vtb = kb  + 4194304;       // V transposed [B*H][HD][T]
    unsigned short* yb  = xb;                  // reuse: x dead after QKV GEMMs

    cvt_kernel<<<4096, 256, 0, stream>>>(x,  xb,  4194304);
    cvt_kernel<<<1024, 256, 0, stream>>>(Wk, wkb, 1048576);
    cvt_kernel<<<1024, 256, 0, stream>>>(Wq, wqb, 1048576);
    cvt_kernel<<<1024, 256, 0, stream>>>(Wv, wvb, 1048576);
    cvt_kernel<<<1024, 256, 0, stream>>>(Wp, wpb, 1048576);

    dim3 gg(Cv / 128, (Bv * Tv) / 128);   // (8, 32)
    gemm_bt<<<gg, 256, 0, stream>>>(xb, wqb, bq, qb, Bv * Tv, Cv, Cv, 0, 0.125f);
    gemm_bt<<<gg, 256, 0, stream>>>(xb, wkb, bk, kb, Bv * Tv, Cv, Cv, 0, 1.0f);
    // V computed transposed: C[c][tok] = sum_k Wv[c][k] * x[tok][k]  (bias by row)
    dim3 gv((Bv * Tv) / 128, Cv / 128);   // (32, 8)
    gemm_bt<<<gv, 256, 0, stream>>>(wvb, xb, bv, vtb, Cv, Bv * Tv, Cv, 2, 1.0f);

    attn_kernel<<<1024, 128, 0, stream>>>(qb, kb, vtb, yb);

    gemm_bt<<<gg, 256, 0, stream>>>(yb, wpb, bp, d_out, Bv * Tv, Cv, Cv, 1, 1.0f);
}

// Round 4
// 262.265 us; speedup vs baseline: 1.2957x; 1.0875x over previous
//
#include <hip/hip_runtime.h>
#include <stdint.h>

// Problem constants
#define Bv  2
#define Tv  2048
#define Cv  1024
#define Hv  16
#define HDv 64
#define LOG2E 1.44269504088896340736f

typedef __bf16 bf16x8 __attribute__((ext_vector_type(8)));
typedef float f32x4 __attribute__((ext_vector_type(4)));
typedef unsigned short us4v __attribute__((ext_vector_type(4)));

static __device__ __forceinline__ unsigned short f2bf(float f) {
    unsigned int u = __builtin_bit_cast(unsigned int, f);
    u += 0x7FFFu + ((u >> 16) & 1u);   // round-to-nearest-even
    return (unsigned short)(u >> 16);
}

static __device__ __forceinline__ unsigned int cvt_pk_bf16(float lo, float hi) {
    unsigned int w;
    asm("v_cvt_pk_bf16_f32 %0, %1, %2" : "=v"(w) : "v"(lo), "v"(hi));
    return w;
}

static __device__ __forceinline__ void gld_lds16(const void* g, void* l) {
    __builtin_amdgcn_global_load_lds(
        (const __attribute__((address_space(1))) void*)g,
        (__attribute__((address_space(3))) void*)l, 16, 0, 0);
}

static __device__ __forceinline__ f32x4 mfma_bf16(bf16x8 a, bf16x8 b, f32x4 c) {
    return __builtin_amdgcn_mfma_f32_16x16x32_bf16(a, b, c, 0, 0, 0);
}

static __device__ __forceinline__ f32x4 fmax4(f32x4 a, f32x4 b) {
    f32x4 r;
    r[0] = fmaxf(a[0], b[0]); r[1] = fmaxf(a[1], b[1]);
    r[2] = fmaxf(a[2], b[2]); r[3] = fmaxf(a[3], b[3]);
    return r;
}

// ---------------- fp32 -> bf16 conversion ----------------
__global__ __launch_bounds__(256) void cvt_kernel(const float* __restrict__ in,
                                                  unsigned short* __restrict__ out,
                                                  int n) {
    int i = (blockIdx.x * 256 + threadIdx.x) * 4;
    if (i >= n) return;
    float4 v = *(const float4*)(in + i);
    us4v o;
    o[0] = f2bf(v.x); o[1] = f2bf(v.y); o[2] = f2bf(v.z); o[3] = f2bf(v.w);
    *(us4v*)(out + i) = o;
}

// ---------------- GEMM: C[m][n] = sum_k A[m][k]*B[n][k] (+bias) ----------------
// Tile 128(M) x 64(N), BK=32, 256 threads (4 waves, 2x2 wave grid, wave=64x32).
// mode 0: fused QK epilogue. n<1024 -> q (scaled by 1/8*log2e, bias0), written to
//         out + 0; n>=1024 -> k (bias1), out + 4194304. Both bf16 head-split.
// mode 1: out fp32 [m*N+n], bias0[n]
// mode 2: out bf16 V-transposed: out[((n>>11)*1024 + m)*Tv + (n&2047)], bias0[m]
__global__ __launch_bounds__(256) void gemm_bt(const unsigned short* __restrict__ A,
                                               const unsigned short* __restrict__ Bm,
                                               const float* __restrict__ bias0,
                                               const float* __restrict__ bias1,
                                               void* __restrict__ out,
                                               int M, int N, int K, int mode, float scale) {
    __shared__ unsigned short As[128 * 32];
    __shared__ unsigned short Bs[64 * 32];

    const int tid  = threadIdx.x;
    const int lane = tid & 63;
    const int w    = tid >> 6;
    const int wr   = w >> 1, wc = w & 1;
    const int m0   = blockIdx.y * 128;
    const int n0   = blockIdx.x * 64;
    const int l16  = lane & 15;
    const int lk8  = (lane >> 4) * 8;

    f32x4 acc[4][2] = {};

    const int srow = tid >> 2;
    const int skc  = (tid & 3) * 8;

    for (int k0 = 0; k0 < K; k0 += 32) {
        const unsigned short* gA0 = A  + (size_t)(m0 + srow)      * K + k0 + skc;
        const unsigned short* gA1 = A  + (size_t)(m0 + srow + 64) * K + k0 + skc;
        const unsigned short* gB0 = Bm + (size_t)(n0 + srow)      * K + k0 + skc;
        gld_lds16(gA0, &As[(size_t)tid * 8]);
        gld_lds16(gA1, &As[(size_t)(tid + 256) * 8]);
        gld_lds16(gB0, &Bs[(size_t)tid * 8]);
        __syncthreads();

        bf16x8 af[4], bf[2];
#pragma unroll
        for (int mf = 0; mf < 4; ++mf)
            af[mf] = *(const bf16x8*)&As[(wr * 64 + mf * 16 + l16) * 32 + lk8];
#pragma unroll
        for (int nf = 0; nf < 2; ++nf)
            bf[nf] = *(const bf16x8*)&Bs[(wc * 32 + nf * 16 + l16) * 32 + lk8];
#pragma unroll
        for (int mf = 0; mf < 4; ++mf)
#pragma unroll
            for (int nf = 0; nf < 2; ++nf)
                acc[mf][nf] = mfma_bf16(af[mf], bf[nf], acc[mf][nf]);
        __syncthreads();
    }

    // epilogue: C/D layout row=(lane>>4)*4+r, col=lane&15
#pragma unroll
    for (int mf = 0; mf < 4; ++mf) {
#pragma unroll
        for (int nf = 0; nf < 2; ++nf) {
#pragma unroll
            for (int r = 0; r < 4; ++r) {
                int m = m0 + wr * 64 + mf * 16 + (lane >> 4) * 4 + r;
                int n = n0 + wc * 32 + nf * 16 + l16;
                if (mode == 0) {
                    int sel = n >> 10, ch = n & 1023;
                    float bia = sel ? bias1[ch] : bias0[ch];
                    float v = (acc[mf][nf][r] + bia) * (sel ? 1.0f : scale);
                    int b = m >> 11, t = m & (Tv - 1);
                    int h = ch >> 6, d = ch & (HDv - 1);
                    ((unsigned short*)out)[(size_t)sel * 4194304 +
                        (((size_t)(b * Hv + h)) * Tv + t) * HDv + d] = f2bf(v);
                } else if (mode == 2) {
                    float v = acc[mf][nf][r] + bias0[m];
                    ((unsigned short*)out)[((size_t)(n >> 11) * 1024 + m) * Tv + (n & (Tv - 1))] = f2bf(v);
                } else {
                    ((float*)out)[(size_t)m * N + n] = acc[mf][nf][r] + bias0[n];
                }
            }
        }
    }
}

// ---------------- causal flash attention (swapped-operand layout) ----------------
// q,k: [B*H][T][HD] bf16 (q pre-scaled by 0.125*log2e). vt: [B*H][HD][T] bf16.
// y: [B][T][C] bf16 (head-merged).
// One 16-q-row task per wave; 2048 blocks x 2 waves = 4096 waves (4/SIMD).
// S^T = K*Q^T so q is lane-local (col=l16); O^T = V^T*P^T keeps stats lane-local.
__global__ __launch_bounds__(128, 4) void attn_kernel(const unsigned short* __restrict__ q,
                                                      const unsigned short* __restrict__ k,
                                                      const unsigned short* __restrict__ vt,
                                                      unsigned short* __restrict__ y) {
    __shared__ __align__(16) unsigned short Pb[2][16 * 132];   // +4 shorts row pad

    const int tid  = threadIdx.x;
    const int lane = tid & 63;
    const int w    = tid >> 6;
    const int l16  = lane & 15;
    const int lk   = lane >> 4;

    // XCD-pinned: lb&7 = xcd (round-robin dispatch); 4 heads per XCD.
    // th<32 ? th : 95-th pairs light/heavy tiles at stride 32 so CU-co-resident
    // blocks get a balanced mix.
    const int lb   = blockIdx.x;
    const int xcd  = lb & 7;
    const int rest = lb >> 3;              // 0..255
    const int bh   = xcd * 4 + (rest >> 6);
    const int th   = rest & 63;
    const int tile = (th < 32) ? th : 95 - th;   // 32-row block tile, bijective

    const int b = bh >> 4, h = bh & (Hv - 1);
    const int qr0 = tile * 32 + w * 16;
    const int qg  = qr0 + l16;
    const size_t head_off = (size_t)bh * (Tv * HDv);
    const unsigned short* kpb = k  + head_off;
    const unsigned short* vpb = vt + head_off;   // [HD][T]
    unsigned short* pb = &Pb[w][0];
    const int prow = l16 * 132;

    // Q as B-fragment: col=q (l16), k-dim = d
    bf16x8 qf0, qf1;
    {
        const unsigned short* qp = q + head_off + (size_t)qg * HDv + lk * 8;
        qf0 = *(const bf16x8*)qp;
        qf1 = *(const bf16x8*)(qp + 32);
    }

    f32x4 acc[4] = {};           // O^T: acc[nt], row d = nt*16+lk*4+r, col q = l16
    float m = -1e38f, l = 0.f;

    const int nkt = (qr0 + 143) >> 7;      // ceil((qr0+16)/128)
    for (int j = 0; j < nkt; ++j) {
        const int kk0 = j * 128;

        // S^T = K Q^T : s[ct][r] = S[k = kk0+ct*16+lk*4+r][q = l16]
        f32x4 s[8];
        __builtin_amdgcn_s_setprio(1);
#pragma unroll
        for (int ct = 0; ct < 8; ++ct) {
            const unsigned short* kp = kpb + (size_t)(kk0 + ct * 16 + l16) * HDv + lk * 8;
            bf16x8 k0 = *(const bf16x8*)kp;
            bf16x8 k1 = *(const bf16x8*)(kp + 32);
            f32x4 z = {};
            z = mfma_bf16(k0, qf0, z);
            z = mfma_bf16(k1, qf1, z);
            s[ct] = z;
        }
        __builtin_amdgcn_s_setprio(0);

        // V^T fragments issued early (independent of softmax) to hide L2 latency
        bf16x8 vf[4][4];
#pragma unroll
        for (int nt = 0; nt < 4; ++nt)
#pragma unroll
            for (int kh = 0; kh < 4; ++kh)
                vf[nt][kh] = *(const bf16x8*)(vpb + (size_t)(nt * 16 + l16) * Tv + kk0 + kh * 32 + lk * 8);

        // causal mask (only tiles overlapping the diagonal)
        if (kk0 + 127 > qr0) {
#pragma unroll
            for (int ct = 0; ct < 8; ++ct) {
                const int kb2 = kk0 + ct * 16 + lk * 4;
#pragma unroll
                for (int r = 0; r < 4; ++r)
                    if (kb2 + r > qg) s[ct][r] = -1e38f;
            }
        }

        // online softmax (base-2 domain; scale folded into q): in-reg fmax tree + 2 shfl
        f32x4 t0 = fmax4(fmax4(s[0], s[1]), fmax4(s[2], s[3]));
        f32x4 t1 = fmax4(fmax4(s[4], s[5]), fmax4(s[6], s[7]));
        t0 = fmax4(t0, t1);
        float pm = fmaxf(fmaxf(t0[0], t0[1]), fmaxf(t0[2], t0[3]));
        pm = fmaxf(pm, __shfl_xor(pm, 16));
        pm = fmaxf(pm, __shfl_xor(pm, 32));

        const float mnew  = fmaxf(m, pm);
        const float alpha = __builtin_exp2f(m - mnew);

#pragma unroll
        for (int ct = 0; ct < 8; ++ct)
#pragma unroll
            for (int r = 0; r < 4; ++r)
                s[ct][r] = __builtin_exp2f(s[ct][r] - mnew);

        f32x4 u0 = (s[0] + s[1]) + (s[2] + s[3]);
        f32x4 u1 = (s[4] + s[5]) + (s[6] + s[7]);
        u0 += u1;
        float psum = (u0[0] + u0[1]) + (u0[2] + u0[3]);
        psum += __shfl_xor(psum, 16);
        psum += __shfl_xor(psum, 32);

        l = l * alpha + psum;
        m = mnew;
#pragma unroll
        for (int nt = 0; nt < 4; ++nt)
            acc[nt] *= alpha;

        // P^T -> LDS rows=q, cols=k (b64 writes, conflict-free via +4 pad)
#pragma unroll
        for (int ct = 0; ct < 8; ++ct) {
            uint2 wv;
            wv.x = cvt_pk_bf16(s[ct][0], s[ct][1]);
            wv.y = cvt_pk_bf16(s[ct][2], s[ct][3]);
            *(uint2*)&pb[prow + ct * 16 + lk * 4] = wv;
        }

        // O^T += V^T * P^T
        __builtin_amdgcn_s_setprio(1);
#pragma unroll
        for (int kh = 0; kh < 4; ++kh) {
            union { us4v p[2]; bf16x8 f; } u;
            u.p[0] = *(const us4v*)&pb[prow + kh * 32 + lk * 8];
            u.p[1] = *(const us4v*)&pb[prow + kh * 32 + lk * 8 + 4];
#pragma unroll
            for (int nt = 0; nt < 4; ++nt)
                acc[nt] = mfma_bf16(vf[nt][kh], u.f, acc[nt]);
        }
        __builtin_amdgcn_s_setprio(0);
    }

    // epilogue: lane-local normalize, packed 8B stores
    const float rl = 1.0f / l;
    const size_t ybase = ((size_t)(b * Tv + qg)) * Cv + h * HDv + lk * 4;
#pragma unroll
    for (int nt = 0; nt < 4; ++nt) {
        uint2 wv;
        wv.x = cvt_pk_bf16(acc[nt][0] * rl, acc[nt][1] * rl);
        wv.y = cvt_pk_bf16(acc[nt][2] * rl, acc[nt][3] * rl);
        *(uint2*)&y[ybase + nt * 16] = wv;
    }
}

extern "C" void kernel_launch(void* const* d_in, const int* in_sizes, int n_in,
                              void* d_out, int out_size, void* d_ws, size_t ws_size,
                              hipStream_t stream) {
    const float* x  = (const float*)d_in[0];
    const float* Wk = (const float*)d_in[1];
    const float* bk = (const float*)d_in[2];
    const float* Wq = (const float*)d_in[3];
    const float* bq = (const float*)d_in[4];
    const float* Wv = (const float*)d_in[5];
    const float* bv = (const float*)d_in[6];
    const float* Wp = (const float*)d_in[7];
    const float* bp = (const float*)d_in[8];

    // workspace layout (ushorts); total 40 MB
    unsigned short* ws   = (unsigned short*)d_ws;
    unsigned short* xb   = ws;                   // 4194304 (reused as yb)
    unsigned short* wqkb = xb   + 4194304;       // 2097152: Wq rows then Wk rows
    unsigned short* wvb  = wqkb + 2097152;       // 1048576
    unsigned short* wpb  = wvb  + 1048576;       // 1048576
    unsigned short* qb   = wpb  + 1048576;       // 4194304, head-split, pre-scaled
    unsigned short* kb   = qb   + 4194304;       // 4194304, head-split (qb+4194304!)
    unsigned short* vtb  = kb   + 4194304;       // 4194304, V^T [B*H][HD][T]
    unsigned short* yb   = xb;                   // reuse: x dead after QKV GEMMs
    (void)kb;

    cvt_kernel<<<4096, 256, 0, stream>>>(x,  xb,   4194304);
    cvt_kernel<<<1024, 256, 0, stream>>>(Wq, wqkb, 1048576);
    cvt_kernel<<<1024, 256, 0, stream>>>(Wk, wqkb + 1048576, 1048576);
    cvt_kernel<<<1024, 256, 0, stream>>>(Wv, wvb,  1048576);
    cvt_kernel<<<1024, 256, 0, stream>>>(Wp, wpb,  1048576);

    // fused Q+K projection: N=2048 -> 32x32 = 1024 blocks (4/CU)
    dim3 gqk(2048 / 64, (Bv * Tv) / 128);
    gemm_bt<<<gqk, 256, 0, stream>>>(xb, wqkb, bq, bk, qb, Bv * Tv, 2048, Cv, 0,
                                     0.125f * LOG2E);
    // V computed transposed: C[c][tok] = sum_k Wv[c][k] * x[tok][k]
    dim3 gv((Bv * Tv) / 64, Cv / 128);    // (64, 8) = 512 blocks
    gemm_bt<<<gv, 256, 0, stream>>>(wvb, xb, bv, bv, vtb, Cv, Bv * Tv, Cv, 2, 1.0f);

    attn_kernel<<<2048, 128, 0, stream>>>(qb, kb, vtb, yb);

    dim3 gp(Cv / 64, (Bv * Tv) / 128);    // (16, 32) = 512 blocks
    gemm_bt<<<gp, 256, 0, stream>>>(yb, wpb, bp, bp, d_out, Bv * Tv, Cv, Cv, 1, 1.0f);
}

// Round 5
// 257.279 us; speedup vs baseline: 1.3208x; 1.0194x over previous
//
#include <hip/hip_runtime.h>
#include <stdint.h>

// Problem constants
#define Bv  2
#define Tv  2048
#define Cv  1024
#define Hv  16
#define HDv 64
#define LOG2E 1.44269504088896340736f

typedef __bf16 bf16x8 __attribute__((ext_vector_type(8)));
typedef float f32x4 __attribute__((ext_vector_type(4)));
typedef unsigned short us4v __attribute__((ext_vector_type(4)));

static __device__ __forceinline__ unsigned short f2bf(float f) {
    unsigned int u = __builtin_bit_cast(unsigned int, f);
    u += 0x7FFFu + ((u >> 16) & 1u);   // round-to-nearest-even
    return (unsigned short)(u >> 16);
}

static __device__ __forceinline__ unsigned int cvt_pk_bf16(float lo, float hi) {
    unsigned int w;
    asm("v_cvt_pk_bf16_f32 %0, %1, %2" : "=v"(w) : "v"(lo), "v"(hi));
    return w;
}

static __device__ __forceinline__ void gld_lds16(const void* g, void* l) {
    __builtin_amdgcn_global_load_lds(
        (const __attribute__((address_space(1))) void*)g,
        (__attribute__((address_space(3))) void*)l, 16, 0, 0);
}

static __device__ __forceinline__ f32x4 mfma_bf16(bf16x8 a, bf16x8 b, f32x4 c) {
    return __builtin_amdgcn_mfma_f32_16x16x32_bf16(a, b, c, 0, 0, 0);
}

static __device__ __forceinline__ f32x4 fmax4(f32x4 a, f32x4 b) {
    f32x4 r;
    r[0] = fmaxf(a[0], b[0]); r[1] = fmaxf(a[1], b[1]);
    r[2] = fmaxf(a[2], b[2]); r[3] = fmaxf(a[3], b[3]);
    return r;
}

// ---------------- fp32 -> bf16 conversion ----------------
__global__ __launch_bounds__(256) void cvt_kernel(const float* __restrict__ in,
                                                  unsigned short* __restrict__ out,
                                                  int n) {
    int i = (blockIdx.x * 256 + threadIdx.x) * 4;
    if (i >= n) return;
    float4 v = *(const float4*)(in + i);
    us4v o;
    o[0] = f2bf(v.x); o[1] = f2bf(v.y); o[2] = f2bf(v.z); o[3] = f2bf(v.w);
    *(us4v*)(out + i) = o;
}

// ---------------- GEMM: C[m][n] = sum_k A[m][k]*B[n][k] (+bias) ----------------
// Tile 128(M) x 64(N), BK=32, 256 threads (4 waves, 2x2 wave grid, wave=64x32).
// mode 0: fused QK epilogue. n<1024 -> q (scaled by 1/8*log2e, bias0), written to
//         out + 0; n>=1024 -> k (bias1), out + 4194304. Both bf16 head-split.
// mode 1: out fp32 [m*N+n], bias0[n]
// mode 2: out bf16 V-transposed: out[((n>>11)*1024 + m)*Tv + (n&2047)], bias0[m]
__global__ __launch_bounds__(256) void gemm_bt(const unsigned short* __restrict__ A,
                                               const unsigned short* __restrict__ Bm,
                                               const float* __restrict__ bias0,
                                               const float* __restrict__ bias1,
                                               void* __restrict__ out,
                                               int M, int N, int K, int mode, float scale) {
    __shared__ unsigned short As[128 * 32];
    __shared__ unsigned short Bs[64 * 32];

    const int tid  = threadIdx.x;
    const int lane = tid & 63;
    const int w    = tid >> 6;
    const int wr   = w >> 1, wc = w & 1;
    const int m0   = blockIdx.y * 128;
    const int n0   = blockIdx.x * 64;
    const int l16  = lane & 15;
    const int lk8  = (lane >> 4) * 8;

    f32x4 acc[4][2] = {};

    const int srow = tid >> 2;
    const int skc  = (tid & 3) * 8;

    for (int k0 = 0; k0 < K; k0 += 32) {
        const unsigned short* gA0 = A  + (size_t)(m0 + srow)      * K + k0 + skc;
        const unsigned short* gA1 = A  + (size_t)(m0 + srow + 64) * K + k0 + skc;
        const unsigned short* gB0 = Bm + (size_t)(n0 + srow)      * K + k0 + skc;
        gld_lds16(gA0, &As[(size_t)tid * 8]);
        gld_lds16(gA1, &As[(size_t)(tid + 256) * 8]);
        gld_lds16(gB0, &Bs[(size_t)tid * 8]);
        __syncthreads();

        bf16x8 af[4], bf[2];
#pragma unroll
        for (int mf = 0; mf < 4; ++mf)
            af[mf] = *(const bf16x8*)&As[(wr * 64 + mf * 16 + l16) * 32 + lk8];
#pragma unroll
        for (int nf = 0; nf < 2; ++nf)
            bf[nf] = *(const bf16x8*)&Bs[(wc * 32 + nf * 16 + l16) * 32 + lk8];
#pragma unroll
        for (int mf = 0; mf < 4; ++mf)
#pragma unroll
            for (int nf = 0; nf < 2; ++nf)
                acc[mf][nf] = mfma_bf16(af[mf], bf[nf], acc[mf][nf]);
        __syncthreads();
    }

    // epilogue: C/D layout row=(lane>>4)*4+r, col=lane&15
#pragma unroll
    for (int mf = 0; mf < 4; ++mf) {
#pragma unroll
        for (int nf = 0; nf < 2; ++nf) {
#pragma unroll
            for (int r = 0; r < 4; ++r) {
                int m = m0 + wr * 64 + mf * 16 + (lane >> 4) * 4 + r;
                int n = n0 + wc * 32 + nf * 16 + l16;
                if (mode == 0) {
                    int sel = n >> 10, ch = n & 1023;
                    float bia = sel ? bias1[ch] : bias0[ch];
                    float v = (acc[mf][nf][r] + bia) * (sel ? 1.0f : scale);
                    int b = m >> 11, t = m & (Tv - 1);
                    int h = ch >> 6, d = ch & (HDv - 1);
                    ((unsigned short*)out)[(size_t)sel * 4194304 +
                        (((size_t)(b * Hv + h)) * Tv + t) * HDv + d] = f2bf(v);
                } else if (mode == 2) {
                    float v = acc[mf][nf][r] + bias0[m];
                    ((unsigned short*)out)[((size_t)(n >> 11) * 1024 + m) * Tv + (n & (Tv - 1))] = f2bf(v);
                } else {
                    ((float*)out)[(size_t)m * N + n] = acc[mf][nf][r] + bias0[n];
                }
            }
        }
    }
}

// ---------------- causal flash attention (swapped-operand layout) ----------------
// q,k: [B*H][T][HD] bf16 (q pre-scaled by 0.125*log2e). vt: [B*H][HD][T] bf16.
// y: [B][T][C] bf16 (head-merged).
// One 16-q-row task per wave; 2048 blocks x 2 waves = 4096 waves.
// NOTE: plain __launch_bounds__(128) — round 4 showed (128,4) forces VGPR->64,
// which evicts the vf[4][4] early V loads and serializes (167us vs 130us).
// VGPR ~112 <= 128 already gives 4 waves/SIMD.
__global__ __launch_bounds__(128) void attn_kernel(const unsigned short* __restrict__ q,
                                                   const unsigned short* __restrict__ k,
                                                   const unsigned short* __restrict__ vt,
                                                   unsigned short* __restrict__ y) {
    __shared__ __align__(16) unsigned short Pb[2][16 * 132];   // +4 shorts row pad

    const int tid  = threadIdx.x;
    const int lane = tid & 63;
    const int w    = tid >> 6;
    const int l16  = lane & 15;
    const int lk   = lane >> 4;

    // XCD-pinned: lb&7 = xcd; 4 heads per XCD; light/heavy tile pairing.
    const int lb   = blockIdx.x;
    const int xcd  = lb & 7;
    const int rest = lb >> 3;              // 0..255
    const int bh   = xcd * 4 + (rest >> 6);
    const int th   = rest & 63;
    const int tile = (th < 32) ? th : 95 - th;   // 32-row block tile, bijective

    const int b = bh >> 4, h = bh & (Hv - 1);
    const int qr0 = tile * 32 + w * 16;
    const int qg  = qr0 + l16;
    const size_t head_off = (size_t)bh * (Tv * HDv);
    const unsigned short* kpb = k  + head_off;
    const unsigned short* vpb = vt + head_off;   // [HD][T]
    unsigned short* pb = &Pb[w][0];
    const int prow = l16 * 132;

    // Q as B-fragment: col=q (l16), k-dim = d
    bf16x8 qf0, qf1;
    {
        const unsigned short* qp = q + head_off + (size_t)qg * HDv + lk * 8;
        qf0 = *(const bf16x8*)qp;
        qf1 = *(const bf16x8*)(qp + 32);
    }

    f32x4 acc[4] = {};           // O^T: acc[nt], row d = nt*16+lk*4+r, col q = l16
    float m = -1e38f, l = 0.f;

    const int nkt = (qr0 + 143) >> 7;      // ceil((qr0+16)/128)
    for (int j = 0; j < nkt; ++j) {
        const int kk0 = j * 128;

        // S^T = K Q^T : s[ct][r] = S[k = kk0+ct*16+lk*4+r][q = l16]
        f32x4 s[8];
        __builtin_amdgcn_s_setprio(1);
#pragma unroll
        for (int ct = 0; ct < 8; ++ct) {
            const unsigned short* kp = kpb + (size_t)(kk0 + ct * 16 + l16) * HDv + lk * 8;
            bf16x8 k0 = *(const bf16x8*)kp;
            bf16x8 k1 = *(const bf16x8*)(kp + 32);
            f32x4 z = {};
            z = mfma_bf16(k0, qf0, z);
            z = mfma_bf16(k1, qf1, z);
            s[ct] = z;
        }
        __builtin_amdgcn_s_setprio(0);

        // V^T fragments issued early (independent of softmax) to hide L2 latency
        bf16x8 vf[4][4];
#pragma unroll
        for (int nt = 0; nt < 4; ++nt)
#pragma unroll
            for (int kh = 0; kh < 4; ++kh)
                vf[nt][kh] = *(const bf16x8*)(vpb + (size_t)(nt * 16 + l16) * Tv + kk0 + kh * 32 + lk * 8);

        // causal mask (only tiles overlapping the diagonal)
        if (kk0 + 127 > qr0) {
#pragma unroll
            for (int ct = 0; ct < 8; ++ct) {
                const int kb2 = kk0 + ct * 16 + lk * 4;
#pragma unroll
                for (int r = 0; r < 4; ++r)
                    if (kb2 + r > qg) s[ct][r] = -1e38f;
            }
        }

        // online softmax (base-2 domain; scale folded into q): in-reg fmax tree + 2 shfl
        f32x4 t0 = fmax4(fmax4(s[0], s[1]), fmax4(s[2], s[3]));
        f32x4 t1 = fmax4(fmax4(s[4], s[5]), fmax4(s[6], s[7]));
        t0 = fmax4(t0, t1);
        float pm = fmaxf(fmaxf(t0[0], t0[1]), fmaxf(t0[2], t0[3]));
        pm = fmaxf(pm, __shfl_xor(pm, 16));
        pm = fmaxf(pm, __shfl_xor(pm, 32));

        // defer-max (T13): skip rescale while per-tile max growth <= 8 (log2 domain)
        if (__all(pm - m <= 8.0f)) {
#pragma unroll
            for (int ct = 0; ct < 8; ++ct)
#pragma unroll
                for (int r = 0; r < 4; ++r)
                    s[ct][r] = __builtin_exp2f(s[ct][r] - m);
        } else {
            const float mnew  = fmaxf(m, pm);
            const float alpha = __builtin_exp2f(m - mnew);
#pragma unroll
            for (int ct = 0; ct < 8; ++ct)
#pragma unroll
                for (int r = 0; r < 4; ++r)
                    s[ct][r] = __builtin_exp2f(s[ct][r] - mnew);
            l *= alpha;
#pragma unroll
            for (int nt = 0; nt < 4; ++nt)
                acc[nt] *= alpha;
            m = mnew;
        }

        f32x4 u0 = (s[0] + s[1]) + (s[2] + s[3]);
        f32x4 u1 = (s[4] + s[5]) + (s[6] + s[7]);
        u0 += u1;
        float psum = (u0[0] + u0[1]) + (u0[2] + u0[3]);
        psum += __shfl_xor(psum, 16);
        psum += __shfl_xor(psum, 32);
        l += psum;

        // P^T -> LDS rows=q, cols=k (b64 writes, conflict-free via +4 pad)
#pragma unroll
        for (int ct = 0; ct < 8; ++ct) {
            uint2 wv;
            wv.x = cvt_pk_bf16(s[ct][0], s[ct][1]);
            wv.y = cvt_pk_bf16(s[ct][2], s[ct][3]);
            *(uint2*)&pb[prow + ct * 16 + lk * 4] = wv;
        }

        // O^T += V^T * P^T
        __builtin_amdgcn_s_setprio(1);
#pragma unroll
        for (int kh = 0; kh < 4; ++kh) {
            union { us4v p[2]; bf16x8 f; } u;
            u.p[0] = *(const us4v*)&pb[prow + kh * 32 + lk * 8];
            u.p[1] = *(const us4v*)&pb[prow + kh * 32 + lk * 8 + 4];
#pragma unroll
            for (int nt = 0; nt < 4; ++nt)
                acc[nt] = mfma_bf16(vf[nt][kh], u.f, acc[nt]);
        }
        __builtin_amdgcn_s_setprio(0);
    }

    // epilogue: lane-local normalize, packed 8B stores
    const float rl = 1.0f / l;
    const size_t ybase = ((size_t)(b * Tv + qg)) * Cv + h * HDv + lk * 4;
#pragma unroll
    for (int nt = 0; nt < 4; ++nt) {
        uint2 wv;
        wv.x = cvt_pk_bf16(acc[nt][0] * rl, acc[nt][1] * rl);
        wv.y = cvt_pk_bf16(acc[nt][2] * rl, acc[nt][3] * rl);
        *(uint2*)&y[ybase + nt * 16] = wv;
    }
}

extern "C" void kernel_launch(void* const* d_in, const int* in_sizes, int n_in,
                              void* d_out, int out_size, void* d_ws, size_t ws_size,
                              hipStream_t stream) {
    const float* x  = (const float*)d_in[0];
    const float* Wk = (const float*)d_in[1];
    const float* bk = (const float*)d_in[2];
    const float* Wq = (const float*)d_in[3];
    const float* bq = (const float*)d_in[4];
    const float* Wv = (const float*)d_in[5];
    const float* bv = (const float*)d_in[6];
    const float* Wp = (const float*)d_in[7];
    const float* bp = (const float*)d_in[8];

    // workspace layout (ushorts); total 40 MB
    unsigned short* ws   = (unsigned short*)d_ws;
    unsigned short* xb   = ws;                   // 4194304 (reused as yb)
    unsigned short* wqkb = xb   + 4194304;       // 2097152: Wq rows then Wk rows
    unsigned short* wvb  = wqkb + 2097152;       // 1048576
    unsigned short* wpb  = wvb  + 1048576;       // 1048576
    unsigned short* qb   = wpb  + 1048576;       // 4194304, head-split, pre-scaled
    unsigned short* kb   = qb   + 4194304;       // 4194304, head-split (qb+4194304!)
    unsigned short* vtb  = kb   + 4194304;       // 4194304, V^T [B*H][HD][T]
    unsigned short* yb   = xb;                   // reuse: x dead after QKV GEMMs
    (void)kb;

    cvt_kernel<<<4096, 256, 0, stream>>>(x,  xb,   4194304);
    cvt_kernel<<<1024, 256, 0, stream>>>(Wq, wqkb, 1048576);
    cvt_kernel<<<1024, 256, 0, stream>>>(Wk, wqkb + 1048576, 1048576);
    cvt_kernel<<<1024, 256, 0, stream>>>(Wv, wvb,  1048576);
    cvt_kernel<<<1024, 256, 0, stream>>>(Wp, wpb,  1048576);

    // fused Q+K projection: N=2048 -> 32x32 = 1024 blocks (4/CU)
    dim3 gqk(2048 / 64, (Bv * Tv) / 128);
    gemm_bt<<<gqk, 256, 0, stream>>>(xb, wqkb, bq, bk, qb, Bv * Tv, 2048, Cv, 0,
                                     0.125f * LOG2E);
    // V computed transposed: C[c][tok] = sum_k Wv[c][k] * x[tok][k]
    dim3 gv((Bv * Tv) / 64, Cv / 128);    // (64, 8) = 512 blocks
    gemm_bt<<<gv, 256, 0, stream>>>(wvb, xb, bv, bv, vtb, Cv, Bv * Tv, Cv, 2, 1.0f);

    attn_kernel<<<2048, 128, 0, stream>>>(qb, kb, vtb, yb);

    dim3 gp(Cv / 64, (Bv * Tv) / 128);    // (16, 32) = 512 blocks
    gemm_bt<<<gp, 256, 0, stream>>>(yb, wpb, bp, bp, d_out, Bv * Tv, Cv, Cv, 1, 1.0f);
}

// Round 6
// 205.055 us; speedup vs baseline: 1.6572x; 1.2547x over previous
//
#include <hip/hip_runtime.h>
#include <stdint.h>

// Problem constants
#define Bv  2
#define Tv  2048
#define Cv  1024
#define Hv  16
#define HDv 64
#define LOG2E 1.44269504088896340736f

typedef __bf16 bf16x8 __attribute__((ext_vector_type(8)));
typedef float f32x4 __attribute__((ext_vector_type(4)));
typedef unsigned short us4v __attribute__((ext_vector_type(4)));

static __device__ __forceinline__ unsigned short f2bf(float f) {
    unsigned int u = __builtin_bit_cast(unsigned int, f);
    u += 0x7FFFu + ((u >> 16) & 1u);   // round-to-nearest-even
    return (unsigned short)(u >> 16);
}

static __device__ __forceinline__ unsigned int cvt_pk_bf16(float lo, float hi) {
    unsigned int w;
    asm("v_cvt_pk_bf16_f32 %0, %1, %2" : "=v"(w) : "v"(lo), "v"(hi));
    return w;
}

static __device__ __forceinline__ void gld_lds16(const void* g, void* l) {
    __builtin_amdgcn_global_load_lds(
        (const __attribute__((address_space(1))) void*)g,
        (__attribute__((address_space(3))) void*)l, 16, 0, 0);
}

static __device__ __forceinline__ f32x4 mfma_bf16(bf16x8 a, bf16x8 b, f32x4 c) {
    return __builtin_amdgcn_mfma_f32_16x16x32_bf16(a, b, c, 0, 0, 0);
}

static __device__ __forceinline__ f32x4 fmax4(f32x4 a, f32x4 b) {
    f32x4 r;
    r[0] = fmaxf(a[0], b[0]); r[1] = fmaxf(a[1], b[1]);
    r[2] = fmaxf(a[2], b[2]); r[3] = fmaxf(a[3], b[3]);
    return r;
}

// ---------------- fp32 -> bf16 conversion ----------------
__global__ __launch_bounds__(256) void cvt_kernel(const float* __restrict__ in,
                                                  unsigned short* __restrict__ out,
                                                  int n) {
    int i = (blockIdx.x * 256 + threadIdx.x) * 4;
    if (i >= n) return;
    float4 v = *(const float4*)(in + i);
    us4v o;
    o[0] = f2bf(v.x); o[1] = f2bf(v.y); o[2] = f2bf(v.z); o[3] = f2bf(v.w);
    *(us4v*)(out + i) = o;
}

// ---------------- GEMM: C[m][n] = sum_k A[m][k]*B[n][k] (+bias) ----------------
// Tile 128(M) x 64(N), BK=32, 256 threads (4 waves, 2x2 wave grid, wave=64x32).
// mode 0: fused QK epilogue. n<1024 -> q (scaled by 1/8*log2e, bias0), written to
//         out + 0; n>=1024 -> k (bias1), out + 4194304. Both bf16 head-split.
// mode 1: out fp32 [m*N+n], bias0[n]
// mode 2: out bf16 V-transposed: out[((n>>11)*1024 + m)*Tv + (n&2047)], bias0[m]
__global__ __launch_bounds__(256) void gemm_bt(const unsigned short* __restrict__ A,
                                               const unsigned short* __restrict__ Bm,
                                               const float* __restrict__ bias0,
                                               const float* __restrict__ bias1,
                                               void* __restrict__ out,
                                               int M, int N, int K, int mode, float scale) {
    __shared__ unsigned short As[128 * 32];
    __shared__ unsigned short Bs[64 * 32];

    const int tid  = threadIdx.x;
    const int lane = tid & 63;
    const int w    = tid >> 6;
    const int wr   = w >> 1, wc = w & 1;
    const int m0   = blockIdx.y * 128;
    const int n0   = blockIdx.x * 64;
    const int l16  = lane & 15;
    const int lk8  = (lane >> 4) * 8;

    f32x4 acc[4][2] = {};

    const int srow = tid >> 2;
    const int skc  = (tid & 3) * 8;

    for (int k0 = 0; k0 < K; k0 += 32) {
        const unsigned short* gA0 = A  + (size_t)(m0 + srow)      * K + k0 + skc;
        const unsigned short* gA1 = A  + (size_t)(m0 + srow + 64) * K + k0 + skc;
        const unsigned short* gB0 = Bm + (size_t)(n0 + srow)      * K + k0 + skc;
        gld_lds16(gA0, &As[(size_t)tid * 8]);
        gld_lds16(gA1, &As[(size_t)(tid + 256) * 8]);
        gld_lds16(gB0, &Bs[(size_t)tid * 8]);
        __syncthreads();

        bf16x8 af[4], bf[2];
#pragma unroll
        for (int mf = 0; mf < 4; ++mf)
            af[mf] = *(const bf16x8*)&As[(wr * 64 + mf * 16 + l16) * 32 + lk8];
#pragma unroll
        for (int nf = 0; nf < 2; ++nf)
            bf[nf] = *(const bf16x8*)&Bs[(wc * 32 + nf * 16 + l16) * 32 + lk8];
#pragma unroll
        for (int mf = 0; mf < 4; ++mf)
#pragma unroll
            for (int nf = 0; nf < 2; ++nf)
                acc[mf][nf] = mfma_bf16(af[mf], bf[nf], acc[mf][nf]);
        __syncthreads();
    }

    // epilogue: C/D layout row=(lane>>4)*4+r, col=lane&15
#pragma unroll
    for (int mf = 0; mf < 4; ++mf) {
#pragma unroll
        for (int nf = 0; nf < 2; ++nf) {
#pragma unroll
            for (int r = 0; r < 4; ++r) {
                int m = m0 + wr * 64 + mf * 16 + (lane >> 4) * 4 + r;
                int n = n0 + wc * 32 + nf * 16 + l16;
                if (mode == 0) {
                    int sel = n >> 10, ch = n & 1023;
                    float bia = sel ? bias1[ch] : bias0[ch];
                    float v = (acc[mf][nf][r] + bia) * (sel ? 1.0f : scale);
                    int b = m >> 11, t = m & (Tv - 1);
                    int h = ch >> 6, d = ch & (HDv - 1);
                    ((unsigned short*)out)[(size_t)sel * 4194304 +
                        (((size_t)(b * Hv + h)) * Tv + t) * HDv + d] = f2bf(v);
                } else if (mode == 2) {
                    float v = acc[mf][nf][r] + bias0[m];
                    ((unsigned short*)out)[((size_t)(n >> 11) * 1024 + m) * Tv + (n & (Tv - 1))] = f2bf(v);
                } else {
                    ((float*)out)[(size_t)m * N + n] = acc[mf][nf][r] + bias0[n];
                }
            }
        }
    }
}

// ---------------- causal flash attention (block-staged K, swapped layout) ----------------
// q,k: [B*H][T][HD] bf16 (q pre-scaled by 0.125*log2e). vt: [B*H][HD][T] bf16.
// y: [B][T][C] bf16 (head-merged).
// Block = 4 waves = one 64-q-row tile; 1024 blocks (all co-resident at 4/CU).
// K tile (64x64) staged in LDS via global_load_lds, double-buffered, XOR-swizzled
// chunks (LDS chunk (r,cs) holds global chunk (r, cs^(r&7)); read applies same XOR
// -> 64-lane b128 reads spread uniformly over all 8 bank-groups = LDS floor).
// V^T read directly from global (L2-resident), issued early to hide latency.
// S^T = K*Q^T so q is lane-local; O^T = V^T*P^T keeps softmax stats lane-local.
__global__ __launch_bounds__(256) void attn_kernel(const unsigned short* __restrict__ q,
                                                   const unsigned short* __restrict__ k,
                                                   const unsigned short* __restrict__ vt,
                                                   unsigned short* __restrict__ y) {
    __shared__ __align__(16) unsigned short Ks[2][64 * 64];   // [buf][r*8 + cs chunks of 16B]
    __shared__ __align__(16) unsigned short Pb[4][16 * 72];   // 72 shorts/row: 16B-aligned rows

    const int tid  = threadIdx.x;
    const int lane = tid & 63;
    const int w    = tid >> 6;
    const int l16  = lane & 15;
    const int lk   = lane >> 4;

    // XCD-pinned: lb&7 = xcd; 4 heads per XCD; heavy tiles first within each head.
    const int lb   = blockIdx.x;
    const int xcd  = lb & 7;
    const int rest = lb >> 3;                 // 0..127
    const int bh   = xcd * 4 + (rest >> 5);
    const int tile = 31 - (rest & 31);        // 64-row q tile, heavy-first

    const int b = bh >> 4, h = bh & (Hv - 1);
    const int qr0 = tile * 64 + w * 16;       // this wave's first q row
    const int qg  = qr0 + l16;
    const size_t head_off = (size_t)bh * (Tv * HDv);
    const unsigned short* kpb = k  + head_off;
    const unsigned short* vpb = vt + head_off;   // [HD][T]
    unsigned short* pb = &Pb[w][0];
    const int prow = l16 * 72;

    // Q as B-fragment: col=q (l16), contraction = d
    bf16x8 qf0, qf1;
    {
        const unsigned short* qp = q + head_off + (size_t)qg * HDv + lk * 8;
        qf0 = *(const bf16x8*)qp;
        qf1 = *(const bf16x8*)(qp + 32);
    }

    f32x4 acc[4] = {};           // O^T: acc[nt], row d = nt*16+lk*4+r, col q = l16
    float m = -1e38f, l = 0.f;
    const int nkt = tile + 1;    // 64-wide K tiles

    // stage K tile [64 rows][8 chunks] with source-side XOR swizzle.
    // chunk id ch = (w*2+i)*64 + lane (lane-linear, 16B stride -> valid gld_lds dest)
    auto stage = [&](int buf, int kk0) {
#pragma unroll
        for (int i = 0; i < 2; ++i) {
            int ch = (w * 2 + i) * 64 + lane;
            int r  = ch >> 3, cs = ch & 7;
            int c  = cs ^ (r & 7);
            gld_lds16(kpb + (size_t)(kk0 + r) * HDv + c * 8, &Ks[buf][ch * 8]);
        }
    };

    int cur = 0;
    stage(0, 0);
    __syncthreads();             // drains vmcnt(0): staging complete

    for (int j = 0; j < nkt; ++j) {
        const int kk0 = j * 64;
        if (j + 1 < nkt) stage(cur ^ 1, kk0 + 64);   // prefetch next tile

        // S^T = K Q^T from LDS: s[ct][r] = S[k = kk0+ct*16+lk*4+r][q = l16]
        f32x4 s[4];
        __builtin_amdgcn_s_setprio(1);
#pragma unroll
        for (int ct = 0; ct < 4; ++ct) {
            const int rr = ct * 16 + l16;
            bf16x8 k0 = *(const bf16x8*)&Ks[cur][(rr * 8 + (lk       ^ (rr & 7))) * 8];
            bf16x8 k1 = *(const bf16x8*)&Ks[cur][(rr * 8 + ((4 + lk) ^ (rr & 7))) * 8];
            f32x4 z = {};
            z = mfma_bf16(k0, qf0, z);
            z = mfma_bf16(k1, qf1, z);
            s[ct] = z;
        }
        __builtin_amdgcn_s_setprio(0);

        // V^T fragments from global, issued early (independent of softmax)
        bf16x8 vf[4][2];
#pragma unroll
        for (int nt = 0; nt < 4; ++nt)
#pragma unroll
            for (int kh = 0; kh < 2; ++kh)
                vf[nt][kh] = *(const bf16x8*)(vpb + (size_t)(nt * 16 + l16) * Tv + kk0 + kh * 32 + lk * 8);

        // causal mask (only the diagonal-overlapping tile)
        if (kk0 + 63 > qr0) {
#pragma unroll
            for (int ct = 0; ct < 4; ++ct) {
                const int kb2 = kk0 + ct * 16 + lk * 4;
#pragma unroll
                for (int r = 0; r < 4; ++r)
                    if (kb2 + r > qg) s[ct][r] = -1e38f;
            }
        }

        // online softmax (base-2; scale folded into q): in-reg fmax tree + 2 shfl
        f32x4 t0 = fmax4(fmax4(s[0], s[1]), fmax4(s[2], s[3]));
        float pm = fmaxf(fmaxf(t0[0], t0[1]), fmaxf(t0[2], t0[3]));
        pm = fmaxf(pm, __shfl_xor(pm, 16));
        pm = fmaxf(pm, __shfl_xor(pm, 32));

        // defer-max (T13): skip rescale while per-tile max growth <= 8 (log2 domain)
        if (__all(pm - m <= 8.0f)) {
#pragma unroll
            for (int ct = 0; ct < 4; ++ct)
#pragma unroll
                for (int r = 0; r < 4; ++r)
                    s[ct][r] = __builtin_exp2f(s[ct][r] - m);
        } else {
            const float mnew  = fmaxf(m, pm);
            const float alpha = __builtin_exp2f(m - mnew);
#pragma unroll
            for (int ct = 0; ct < 4; ++ct)
#pragma unroll
                for (int r = 0; r < 4; ++r)
                    s[ct][r] = __builtin_exp2f(s[ct][r] - mnew);
            l *= alpha;
#pragma unroll
            for (int nt = 0; nt < 4; ++nt)
                acc[nt] *= alpha;
            m = mnew;
        }

        f32x4 u0 = (s[0] + s[1]) + (s[2] + s[3]);
        float psum = (u0[0] + u0[1]) + (u0[2] + u0[3]);
        psum += __shfl_xor(psum, 16);
        psum += __shfl_xor(psum, 32);
        l += psum;

        // P^T -> LDS rows=q (72-short stride: 16B-aligned, uniform bank spread)
#pragma unroll
        for (int ct = 0; ct < 4; ++ct) {
            uint2 wv;
            wv.x = cvt_pk_bf16(s[ct][0], s[ct][1]);
            wv.y = cvt_pk_bf16(s[ct][2], s[ct][3]);
            *(uint2*)&pb[prow + ct * 16 + lk * 4] = wv;
        }

        // O^T += V^T * P^T
        __builtin_amdgcn_s_setprio(1);
#pragma unroll
        for (int kh = 0; kh < 2; ++kh) {
            union { us4v p[2]; bf16x8 f; } u;
            u.p[0] = *(const us4v*)&pb[prow + kh * 32 + lk * 8];
            u.p[1] = *(const us4v*)&pb[prow + kh * 32 + lk * 8 + 4];
#pragma unroll
            for (int nt = 0; nt < 4; ++nt)
                acc[nt] = mfma_bf16(vf[nt][kh], u.f, acc[nt]);
        }
        __builtin_amdgcn_s_setprio(0);

        __syncthreads();          // all waves done with Ks[cur]; prefetch landed
        cur ^= 1;
    }

    // epilogue: lane-local normalize, packed 8B stores
    const float rl = 1.0f / l;
    const size_t ybase = ((size_t)(b * Tv + qg)) * Cv + h * HDv + lk * 4;
#pragma unroll
    for (int nt = 0; nt < 4; ++nt) {
        uint2 wv;
        wv.x = cvt_pk_bf16(acc[nt][0] * rl, acc[nt][1] * rl);
        wv.y = cvt_pk_bf16(acc[nt][2] * rl, acc[nt][3] * rl);
        *(uint2*)&y[ybase + nt * 16] = wv;
    }
}

extern "C" void kernel_launch(void* const* d_in, const int* in_sizes, int n_in,
                              void* d_out, int out_size, void* d_ws, size_t ws_size,
                              hipStream_t stream) {
    const float* x  = (const float*)d_in[0];
    const float* Wk = (const float*)d_in[1];
    const float* bk = (const float*)d_in[2];
    const float* Wq = (const float*)d_in[3];
    const float* bq = (const float*)d_in[4];
    const float* Wv = (const float*)d_in[5];
    const float* bv = (const float*)d_in[6];
    const float* Wp = (const float*)d_in[7];
    const float* bp = (const float*)d_in[8];

    // workspace layout (ushorts); total 40 MB
    unsigned short* ws   = (unsigned short*)d_ws;
    unsigned short* xb   = ws;                   // 4194304 (reused as yb)
    unsigned short* wqkb = xb   + 4194304;       // 2097152: Wq rows then Wk rows
    unsigned short* wvb  = wqkb + 2097152;       // 1048576
    unsigned short* wpb  = wvb  + 1048576;       // 1048576
    unsigned short* qb   = wpb  + 1048576;       // 4194304, head-split, pre-scaled
    unsigned short* kb   = qb   + 4194304;       // 4194304, head-split (qb+4194304!)
    unsigned short* vtb  = kb   + 4194304;       // 4194304, V^T [B*H][HD][T]
    unsigned short* yb   = xb;                   // reuse: x dead after QKV GEMMs
    (void)kb;

    cvt_kernel<<<4096, 256, 0, stream>>>(x,  xb,   4194304);
    cvt_kernel<<<1024, 256, 0, stream>>>(Wq, wqkb, 1048576);
    cvt_kernel<<<1024, 256, 0, stream>>>(Wk, wqkb + 1048576, 1048576);
    cvt_kernel<<<1024, 256, 0, stream>>>(Wv, wvb,  1048576);
    cvt_kernel<<<1024, 256, 0, stream>>>(Wp, wpb,  1048576);

    // fused Q+K projection: N=2048 -> 32x32 = 1024 blocks (4/CU)
    dim3 gqk(2048 / 64, (Bv * Tv) / 128);
    gemm_bt<<<gqk, 256, 0, stream>>>(xb, wqkb, bq, bk, qb, Bv * Tv, 2048, Cv, 0,
                                     0.125f * LOG2E);
    // V computed transposed: C[c][tok] = sum_k Wv[c][k] * x[tok][k]
    dim3 gv((Bv * Tv) / 64, Cv / 128);    // (64, 8) = 512 blocks
    gemm_bt<<<gv, 256, 0, stream>>>(wvb, xb, bv, bv, vtb, Cv, Bv * Tv, Cv, 2, 1.0f);

    attn_kernel<<<1024, 256, 0, stream>>>(qb, kb, vtb, yb);

    dim3 gp(Cv / 64, (Bv * Tv) / 128);    // (16, 32) = 512 blocks
    gemm_bt<<<gp, 256, 0, stream>>>(yb, wpb, bp, bp, d_out, Bv * Tv, Cv, Cv, 1, 1.0f);
}

// Round 7
// 183.920 us; speedup vs baseline: 1.8476x; 1.1149x over previous
//
#include <hip/hip_runtime.h>
#include <stdint.h>

// Problem constants
#define Bv  2
#define Tv  2048
#define Cv  1024
#define Hv  16
#define HDv 64
#define LOG2E 1.44269504088896340736f

typedef __bf16 bf16x8 __attribute__((ext_vector_type(8)));
typedef float f32x4 __attribute__((ext_vector_type(4)));
typedef unsigned short us4v __attribute__((ext_vector_type(4)));

static __device__ __forceinline__ unsigned short f2bf(float f) {
    unsigned int u = __builtin_bit_cast(unsigned int, f);
    u += 0x7FFFu + ((u >> 16) & 1u);   // round-to-nearest-even
    return (unsigned short)(u >> 16);
}

static __device__ __forceinline__ unsigned int cvt_pk_bf16(float lo, float hi) {
    unsigned int w;
    asm("v_cvt_pk_bf16_f32 %0, %1, %2" : "=v"(w) : "v"(lo), "v"(hi));
    return w;
}

static __device__ __forceinline__ void gld_lds16(const void* g, void* l) {
    __builtin_amdgcn_global_load_lds(
        (const __attribute__((address_space(1))) void*)g,
        (__attribute__((address_space(3))) void*)l, 16, 0, 0);
}

static __device__ __forceinline__ f32x4 mfma_bf16(bf16x8 a, bf16x8 b, f32x4 c) {
    return __builtin_amdgcn_mfma_f32_16x16x32_bf16(a, b, c, 0, 0, 0);
}

static __device__ __forceinline__ f32x4 fmax4(f32x4 a, f32x4 b) {
    f32x4 r;
    r[0] = fmaxf(a[0], b[0]); r[1] = fmaxf(a[1], b[1]);
    r[2] = fmaxf(a[2], b[2]); r[3] = fmaxf(a[3], b[3]);
    return r;
}

// ---------------- fp32 -> bf16 conversion ----------------
__global__ __launch_bounds__(256) void cvt_kernel(const float* __restrict__ in,
                                                  unsigned short* __restrict__ out,
                                                  int n) {
    int i = (blockIdx.x * 256 + threadIdx.x) * 4;
    if (i >= n) return;
    float4 v = *(const float4*)(in + i);
    us4v o;
    o[0] = f2bf(v.x); o[1] = f2bf(v.y); o[2] = f2bf(v.z); o[3] = f2bf(v.w);
    *(us4v*)(out + i) = o;
}

// 4 weight matrices (1M elements each) in one launch
__global__ __launch_bounds__(256) void cvt4_kernel(const float* __restrict__ a,
                                                   const float* __restrict__ b,
                                                   const float* __restrict__ c,
                                                   const float* __restrict__ d,
                                                   unsigned short* __restrict__ oa,
                                                   unsigned short* __restrict__ ob,
                                                   unsigned short* __restrict__ oc,
                                                   unsigned short* __restrict__ od) {
    const int sel = blockIdx.x >> 10;
    const float* in = sel == 0 ? a : sel == 1 ? b : sel == 2 ? c : d;
    unsigned short* out = sel == 0 ? oa : sel == 1 ? ob : sel == 2 ? oc : od;
    int i = ((blockIdx.x & 1023) * 256 + threadIdx.x) * 4;
    float4 v = *(const float4*)(in + i);
    us4v o;
    o[0] = f2bf(v.x); o[1] = f2bf(v.y); o[2] = f2bf(v.z); o[3] = f2bf(v.w);
    *(us4v*)(out + i) = o;
}

// ---------------- GEMM 128x128, BK=32 (m97 structure): fused QK ----------------
// C[m][n] = sum_k A[m][k]*B[n][k]. n<1024 -> q (scaled by 1/8*log2e, bias0) at out;
// n>=1024 -> k (bias1) at out+4194304. Both bf16 head-split [((b*H+h)*T+t)*HD+d].
__global__ __launch_bounds__(256) void gemm_qk(const unsigned short* __restrict__ A,
                                               const unsigned short* __restrict__ Bm,
                                               const float* __restrict__ bias0,
                                               const float* __restrict__ bias1,
                                               unsigned short* __restrict__ out,
                                               float scale) {
    __shared__ unsigned short As[128 * 32];
    __shared__ unsigned short Bs[128 * 32];
    const int K = Cv;

    const int tid  = threadIdx.x;
    const int lane = tid & 63;
    const int w    = tid >> 6;
    const int wr   = w >> 1, wc = w & 1;
    const int m0   = blockIdx.y * 128;
    const int n0   = blockIdx.x * 128;
    const int l16  = lane & 15;
    const int lk8  = (lane >> 4) * 8;

    f32x4 acc[4][4] = {};
    const int srow = tid >> 2;
    const int skc  = (tid & 3) * 8;

    for (int k0 = 0; k0 < K; k0 += 32) {
        gld_lds16(A  + (size_t)(m0 + srow)      * K + k0 + skc, &As[(size_t)tid * 8]);
        gld_lds16(A  + (size_t)(m0 + srow + 64) * K + k0 + skc, &As[(size_t)(tid + 256) * 8]);
        gld_lds16(Bm + (size_t)(n0 + srow)      * K + k0 + skc, &Bs[(size_t)tid * 8]);
        gld_lds16(Bm + (size_t)(n0 + srow + 64) * K + k0 + skc, &Bs[(size_t)(tid + 256) * 8]);
        __syncthreads();

        bf16x8 af[4], bf[4];
#pragma unroll
        for (int mf = 0; mf < 4; ++mf)
            af[mf] = *(const bf16x8*)&As[(wr * 64 + mf * 16 + l16) * 32 + lk8];
#pragma unroll
        for (int nf = 0; nf < 4; ++nf)
            bf[nf] = *(const bf16x8*)&Bs[(wc * 64 + nf * 16 + l16) * 32 + lk8];
#pragma unroll
        for (int mf = 0; mf < 4; ++mf)
#pragma unroll
            for (int nf = 0; nf < 4; ++nf)
                acc[mf][nf] = mfma_bf16(af[mf], bf[nf], acc[mf][nf]);
        __syncthreads();
    }

#pragma unroll
    for (int mf = 0; mf < 4; ++mf)
#pragma unroll
        for (int nf = 0; nf < 4; ++nf)
#pragma unroll
            for (int r = 0; r < 4; ++r) {
                int m = m0 + wr * 64 + mf * 16 + (lane >> 4) * 4 + r;
                int n = n0 + wc * 64 + nf * 16 + l16;
                int sel = n >> 10, ch = n & 1023;
                float bia = sel ? bias1[ch] : bias0[ch];
                float v = (acc[mf][nf][r] + bia) * (sel ? 1.0f : scale);
                int b = m >> 11, t = m & (Tv - 1);
                int h = ch >> 6, d = ch & (HDv - 1);
                out[(size_t)sel * 4194304 +
                    (((size_t)(b * Hv + h)) * Tv + t) * HDv + d] = f2bf(v);
            }
}

// ---------------- GEMM 128(M)x64(N), BK=64, XOR-swizzled LDS ----------------
// mode 1: out fp32 [m*N+n], bias0[n].  mode 2: out bf16 V^T, bias0[m].
__global__ __launch_bounds__(256) void gemm_64(const unsigned short* __restrict__ A,
                                               const unsigned short* __restrict__ Bm,
                                               const float* __restrict__ bias0,
                                               void* __restrict__ out,
                                               int N, int K, int mode) {
    __shared__ unsigned short As[128 * 64];   // [row][8 chunks of 8, chunk cs holds global cs^(row&7)]
    __shared__ unsigned short Bs[64 * 64];

    const int tid  = threadIdx.x;
    const int lane = tid & 63;
    const int w    = tid >> 6;
    const int wr   = w >> 1, wc = w & 1;
    const int m0   = blockIdx.y * 128;
    const int n0   = blockIdx.x * 64;
    const int l16  = lane & 15;
    const int lk   = (lane >> 4);

    f32x4 acc[4][2] = {};

    for (int k0 = 0; k0 < K; k0 += 64) {
#pragma unroll
        for (int i = 0; i < 4; ++i) {
            int ch = i * 256 + tid, r = ch >> 3, cs = ch & 7, c = cs ^ (r & 7);
            gld_lds16(A + (size_t)(m0 + r) * K + k0 + c * 8, &As[(size_t)ch * 8]);
        }
#pragma unroll
        for (int i = 0; i < 2; ++i) {
            int ch = i * 256 + tid, r = ch >> 3, cs = ch & 7, c = cs ^ (r & 7);
            gld_lds16(Bm + (size_t)(n0 + r) * K + k0 + c * 8, &Bs[(size_t)ch * 8]);
        }
        __syncthreads();

#pragma unroll
        for (int ks = 0; ks < 2; ++ks) {
            bf16x8 af[4], bf[2];
#pragma unroll
            for (int mf = 0; mf < 4; ++mf) {
                int row = wr * 64 + mf * 16 + l16;
                af[mf] = *(const bf16x8*)&As[(row * 8 + ((ks * 4 + lk) ^ (row & 7))) * 8];
            }
#pragma unroll
            for (int nf = 0; nf < 2; ++nf) {
                int row = wc * 32 + nf * 16 + l16;
                bf[nf] = *(const bf16x8*)&Bs[(row * 8 + ((ks * 4 + lk) ^ (row & 7))) * 8];
            }
#pragma unroll
            for (int mf = 0; mf < 4; ++mf)
#pragma unroll
                for (int nf = 0; nf < 2; ++nf)
                    acc[mf][nf] = mfma_bf16(af[mf], bf[nf], acc[mf][nf]);
        }
        __syncthreads();
    }

#pragma unroll
    for (int mf = 0; mf < 4; ++mf)
#pragma unroll
        for (int nf = 0; nf < 2; ++nf)
#pragma unroll
            for (int r = 0; r < 4; ++r) {
                int m = m0 + wr * 64 + mf * 16 + (lane >> 4) * 4 + r;
                int n = n0 + wc * 32 + nf * 16 + l16;
                if (mode == 2) {
                    float v = acc[mf][nf][r] + bias0[m];
                    ((unsigned short*)out)[((size_t)(n >> 11) * 1024 + m) * Tv + (n & (Tv - 1))] = f2bf(v);
                } else {
                    ((float*)out)[(size_t)m * N + n] = acc[mf][nf][r] + bias0[n];
                }
            }
}

// ---------------- causal flash attention (block-staged K, swapped layout) ----------------
// Block = 4 waves = one 64-q-row tile; 1024 blocks (all co-resident at 4/CU).
// Load balance: per (xcd,head), odd heads take complementary tiles (t vs 31-t), so
// each CU's 4 co-resident blocks (same tl, heads differing) sum to a constant 66 kt-units.
__global__ __launch_bounds__(256) void attn_kernel(const unsigned short* __restrict__ q,
                                                   const unsigned short* __restrict__ k,
                                                   const unsigned short* __restrict__ vt,
                                                   unsigned short* __restrict__ y) {
    __shared__ __align__(16) unsigned short Ks[2][64 * 64];   // [buf][r*8 + cs chunks of 16B]
    __shared__ __align__(16) unsigned short Pb[4][16 * 72];   // 72 shorts/row

    const int tid  = threadIdx.x;
    const int lane = tid & 63;
    const int w    = tid >> 6;
    const int l16  = lane & 15;
    const int lk   = lane >> 4;

    const int lb   = blockIdx.x;
    const int xcd  = lb & 7;
    const int rest = lb >> 3;                 // 0..127
    const int bh   = xcd * 4 + (rest >> 5);
    const int tl   = rest & 31;
    const int tile = ((rest >> 5) & 1) ? (31 - tl) : tl;   // complementary pairing

    const int b = bh >> 4, h = bh & (Hv - 1);
    const int qr0 = tile * 64 + w * 16;       // this wave's first q row
    const int qg  = qr0 + l16;
    const size_t head_off = (size_t)bh * (Tv * HDv);
    const unsigned short* kpb = k  + head_off;
    const unsigned short* vpb = vt + head_off;   // [HD][T]
    unsigned short* pb = &Pb[w][0];
    const int prow = l16 * 72;

    // Q as B-fragment: col=q (l16), contraction = d
    bf16x8 qf0, qf1;
    {
        const unsigned short* qp = q + head_off + (size_t)qg * HDv + lk * 8;
        qf0 = *(const bf16x8*)qp;
        qf1 = *(const bf16x8*)(qp + 32);
    }

    f32x4 acc[4] = {};           // O^T: acc[nt], row d = nt*16+lk*4+r, col q = l16
    float m = -1e38f, l = 0.f;
    const int nkt = tile + 1;    // 64-wide K tiles

    auto stage = [&](int buf, int kk0) {
#pragma unroll
        for (int i = 0; i < 2; ++i) {
            int ch = (w * 2 + i) * 64 + lane;
            int r  = ch >> 3, cs = ch & 7;
            int c  = cs ^ (r & 7);
            gld_lds16(kpb + (size_t)(kk0 + r) * HDv + c * 8, &Ks[buf][ch * 8]);
        }
    };

    int cur = 0;
    stage(0, 0);
    __syncthreads();

    for (int j = 0; j < nkt; ++j) {
        const int kk0 = j * 64;
        if (j + 1 < nkt) stage(cur ^ 1, kk0 + 64);   // prefetch next tile

        // S^T = K Q^T from LDS
        f32x4 s[4];
        __builtin_amdgcn_s_setprio(1);
#pragma unroll
        for (int ct = 0; ct < 4; ++ct) {
            const int rr = ct * 16 + l16;
            bf16x8 k0 = *(const bf16x8*)&Ks[cur][(rr * 8 + (lk       ^ (rr & 7))) * 8];
            bf16x8 k1 = *(const bf16x8*)&Ks[cur][(rr * 8 + ((4 + lk) ^ (rr & 7))) * 8];
            f32x4 z = {};
            z = mfma_bf16(k0, qf0, z);
            z = mfma_bf16(k1, qf1, z);
            s[ct] = z;
        }
        __builtin_amdgcn_s_setprio(0);

        // V^T fragments from global, issued early
        bf16x8 vf[4][2];
#pragma unroll
        for (int nt = 0; nt < 4; ++nt)
#pragma unroll
            for (int kh = 0; kh < 2; ++kh)
                vf[nt][kh] = *(const bf16x8*)(vpb + (size_t)(nt * 16 + l16) * Tv + kk0 + kh * 32 + lk * 8);

        // causal mask (diagonal tile only)
        if (kk0 + 63 > qr0) {
#pragma unroll
            for (int ct = 0; ct < 4; ++ct) {
                const int kb2 = kk0 + ct * 16 + lk * 4;
#pragma unroll
                for (int r = 0; r < 4; ++r)
                    if (kb2 + r > qg) s[ct][r] = -1e38f;
            }
        }

        // online softmax (base-2; scale folded into q)
        f32x4 t0 = fmax4(fmax4(s[0], s[1]), fmax4(s[2], s[3]));
        float pm = fmaxf(fmaxf(t0[0], t0[1]), fmaxf(t0[2], t0[3]));
        pm = fmaxf(pm, __shfl_xor(pm, 16));
        pm = fmaxf(pm, __shfl_xor(pm, 32));

        if (__all(pm - m <= 8.0f)) {          // defer-max (T13)
#pragma unroll
            for (int ct = 0; ct < 4; ++ct)
#pragma unroll
                for (int r = 0; r < 4; ++r)
                    s[ct][r] = __builtin_exp2f(s[ct][r] - m);
        } else {
            const float mnew  = fmaxf(m, pm);
            const float alpha = __builtin_exp2f(m - mnew);
#pragma unroll
            for (int ct = 0; ct < 4; ++ct)
#pragma unroll
                for (int r = 0; r < 4; ++r)
                    s[ct][r] = __builtin_exp2f(s[ct][r] - mnew);
            l *= alpha;
#pragma unroll
            for (int nt = 0; nt < 4; ++nt)
                acc[nt] *= alpha;
            m = mnew;
        }

        f32x4 u0 = (s[0] + s[1]) + (s[2] + s[3]);
        float psum = (u0[0] + u0[1]) + (u0[2] + u0[3]);
        psum += __shfl_xor(psum, 16);
        psum += __shfl_xor(psum, 32);
        l += psum;

        // P^T -> LDS rows=q
#pragma unroll
        for (int ct = 0; ct < 4; ++ct) {
            uint2 wv;
            wv.x = cvt_pk_bf16(s[ct][0], s[ct][1]);
            wv.y = cvt_pk_bf16(s[ct][2], s[ct][3]);
            *(uint2*)&pb[prow + ct * 16 + lk * 4] = wv;
        }

        // O^T += V^T * P^T
        __builtin_amdgcn_s_setprio(1);
#pragma unroll
        for (int kh = 0; kh < 2; ++kh) {
            union { us4v p[2]; bf16x8 f; } u;
            u.p[0] = *(const us4v*)&pb[prow + kh * 32 + lk * 8];
            u.p[1] = *(const us4v*)&pb[prow + kh * 32 + lk * 8 + 4];
#pragma unroll
            for (int nt = 0; nt < 4; ++nt)
                acc[nt] = mfma_bf16(vf[nt][kh], u.f, acc[nt]);
        }
        __builtin_amdgcn_s_setprio(0);

        __syncthreads();
        cur ^= 1;
    }

    // epilogue
    const float rl = 1.0f / l;
    const size_t ybase = ((size_t)(b * Tv + qg)) * Cv + h * HDv + lk * 4;
#pragma unroll
    for (int nt = 0; nt < 4; ++nt) {
        uint2 wv;
        wv.x = cvt_pk_bf16(acc[nt][0] * rl, acc[nt][1] * rl);
        wv.y = cvt_pk_bf16(acc[nt][2] * rl, acc[nt][3] * rl);
        *(uint2*)&y[ybase + nt * 16] = wv;
    }
}

extern "C" void kernel_launch(void* const* d_in, const int* in_sizes, int n_in,
                              void* d_out, int out_size, void* d_ws, size_t ws_size,
                              hipStream_t stream) {
    const float* x  = (const float*)d_in[0];
    const float* Wk = (const float*)d_in[1];
    const float* bk = (const float*)d_in[2];
    const float* Wq = (const float*)d_in[3];
    const float* bq = (const float*)d_in[4];
    const float* Wv = (const float*)d_in[5];
    const float* bv = (const float*)d_in[6];
    const float* Wp = (const float*)d_in[7];
    const float* bp = (const float*)d_in[8];

    // workspace layout (ushorts); total 40 MB
    unsigned short* ws   = (unsigned short*)d_ws;
    unsigned short* xb   = ws;                   // 4194304 (reused as yb)
    unsigned short* wqkb = xb   + 4194304;       // 2097152: Wq rows then Wk rows
    unsigned short* wvb  = wqkb + 2097152;       // 1048576
    unsigned short* wpb  = wvb  + 1048576;       // 1048576
    unsigned short* qb   = wpb  + 1048576;       // 4194304, head-split, pre-scaled
    unsigned short* kb   = qb   + 4194304;       // 4194304, head-split (qb+4194304!)
    unsigned short* vtb  = kb   + 4194304;       // 4194304, V^T [B*H][HD][T]
    unsigned short* yb   = xb;                   // reuse: x dead after QKV GEMMs
    (void)kb;

    cvt_kernel<<<4096, 256, 0, stream>>>(x, xb, 4194304);
    cvt4_kernel<<<4096, 256, 0, stream>>>(Wq, Wk, Wv, Wp,
                                          wqkb, wqkb + 1048576, wvb, wpb);

    // fused Q+K projection: 128x128 tiles, grid (16,32) = 512 blocks (2/CU)
    dim3 gqk(2048 / 128, (Bv * Tv) / 128);
    gemm_qk<<<gqk, 256, 0, stream>>>(xb, wqkb, bq, bk, qb, 0.125f * LOG2E);
    // V^T: C[c][tok] = sum_k Wv[c][k]*x[tok][k]; 128x64, BK=64, grid (64,8)=512
    dim3 gv((Bv * Tv) / 64, Cv / 128);
    gemm_64<<<gv, 256, 0, stream>>>(wvb, xb, bv, vtb, Bv * Tv, Cv, 2);

    attn_kernel<<<1024, 256, 0, stream>>>(qb, kb, vtb, yb);

    // output projection: 128x64, BK=64, grid (16,32)=512
    dim3 gp(Cv / 64, (Bv * Tv) / 128);
    gemm_64<<<gp, 256, 0, stream>>>(yb, wpb, bp, d_out, Cv, Cv, 1);
}